// Round 4
// baseline (504.376 us; speedup 1.0000x reference)
//
#include <hip/hip_runtime.h>
#include <cstdint>

#define NTOK 8192

typedef __attribute__((ext_vector_type(4))) float f32x4;
typedef __attribute__((ext_vector_type(8))) short s16x8;
typedef __attribute__((ext_vector_type(4))) short s16x4;

__device__ __forceinline__ short f2bf(float f) {
  union { float f; unsigned u; } x; x.f = f;
  unsigned r = x.u + 0x7FFFu + ((x.u >> 16) & 1u);
  return (short)(r >> 16);
}
__device__ __forceinline__ float bf2f(short s) {
  union { float f; unsigned u; } x;
  x.u = ((unsigned)(unsigned short)s) << 16;
  return x.f;
}
__device__ __forceinline__ void gl_lds16(const void* g, void* l) {
  __builtin_amdgcn_global_load_lds((const unsigned int*)g, (unsigned int*)l, 16, 0, 0);
}

// ---------------------------------------------------------------------------
// K1: transpose (B,DIM,L)->(B,L,DIM) + LayerNorm both inputs (bf16 out),
// seqT f32; converts 4 big weight matrices to bf16; block 0 zeroes the
// lookback flags for fused_scan (stream-ordered before it runs).
// grid: 512 blocks, 256 threads
// ---------------------------------------------------------------------------
__global__ __launch_bounds__(256) void ln_transpose_kernel(
    const float* __restrict__ in0, const float* __restrict__ in1,
    const float* __restrict__ w0, const float* __restrict__ b0,
    const float* __restrict__ w1, const float* __restrict__ b1,
    const float* __restrict__ wxp, const float* __restrict__ wzp,
    const float* __restrict__ wop, const float* __restrict__ wcp,
    short* __restrict__ Wx, short* __restrict__ Wz,
    short* __restrict__ Wo, short* __restrict__ Wc,
    short* __restrict__ xlnz, float* __restrict__ seqT,
    int* __restrict__ flags)
{
  __shared__ float tile[32 * 257];
  __shared__ float mu[32], rs[32];
  const int tid  = threadIdx.x;
  const int pass = blockIdx.x >> 8;
  const int b    = (blockIdx.x >> 7) & 1;
  const int l0   = (blockIdx.x & 127) << 5;

  if (blockIdx.x == 0) {
    #pragma unroll
    for (int i = 0; i < 4; ++i) flags[(i << 8) + tid] = 0;
  }

  // weight conversion: 1024 elements per block (512*1024 = 524288 total)
  {
    int base = (int)blockIdx.x << 10;
    #pragma unroll
    for (int i = 0; i < 4; ++i) {
      int idx = base + (i << 8) + tid;
      if (idx < 65536)       Wx[idx] = f2bf(wxp[idx]);
      else if (idx < 131072) Wz[idx - 65536] = f2bf(wzp[idx - 65536]);
      else if (idx < 196608) Wo[idx - 131072] = f2bf(wop[idx - 131072]);
      else {
        int k = idx - 196608;            // 1280x256 padded
        Wc[k] = ((k >> 8) < 1200) ? f2bf(wcp[k]) : (short)0;
      }
    }
  }

  const float* in = pass ? in1 : in0;
  #pragma unroll 8
  for (int i = 0; i < 32; ++i) {
    int e = (i << 8) + tid;
    int c = e >> 5, lo = e & 31;
    tile[lo * 257 + c] = in[((size_t)(b * 256 + c) << 12) + l0 + lo];
  }
  __syncthreads();
  if (tid < 64) {               // one wave: 32 rows x 2 halves (order-preserving)
    int r = tid & 31, hh = tid >> 5;
    float s = 0.f, ss = 0.f;
    #pragma unroll 16
    for (int c = hh * 128; c < hh * 128 + 128; ++c) {
      float v = tile[r * 257 + c];
      s += v; ss += v * v;
    }
    s  += __shfl_xor(s, 32, 64);
    ss += __shfl_xor(ss, 32, 64);
    if (hh == 0) {
      float m = s * (1.f / 256.f);
      mu[r] = m;
      rs[r] = rsqrtf(ss * (1.f / 256.f) - m * m + 1e-5f);
    }
  }
  __syncthreads();
  const float* w  = pass ? w1 : w0;
  const float* bb = pass ? b1 : b0;
  float wv = w[tid], bv = bb[tid];
  #pragma unroll 8
  for (int i = 0; i < 32; ++i) {
    float v = tile[i * 257 + tid];
    int row = (pass ? 8192 : 0) + (b << 12) + l0 + i;
    xlnz[(size_t)row * 256 + tid] = f2bf((v - mu[i]) * rs[i] * wv + bv);
    if (pass == 0) seqT[(((size_t)b << 12) + l0 + i) * 256 + tid] = v;
  }
}

// ---------------------------------------------------------------------------
// K2: fast 128x128 bf16 MFMA GEMM, C[M,N] = A[M,256] * W[N,256]^T
// Double-buffered LDS, single barrier per K-step.
// EPI 0: f32 store N=256; W switches W0->W1 at m>=Msplit (in_proj x|z)
// EPI 2: conv3d: transposed nontemporal f32x4 store + bias[n]
// ---------------------------------------------------------------------------
template <int EPI>
__global__ __launch_bounds__(256) void gemm_fast(
    const short* __restrict__ A, const short* __restrict__ W0,
    const short* __restrict__ W1, float* __restrict__ Cf,
    short* __restrict__ Cb, const float* __restrict__ ADD,
    const float* __restrict__ bias, int Msplit)
{
  __shared__ short As[2][4096];   // [buf][128][32] bf16 (global_load_lds layout)
  __shared__ short Bs[2][4096];
  const int tid  = threadIdx.x;
  const int lane = tid & 63, wave = tid >> 6;
  const int m0 = blockIdx.y << 7;
  const int n0 = blockIdx.x << 7;
  const short* W = (EPI == 0 && m0 >= Msplit) ? W1 : W0;

  const int sr = tid >> 2;
  const int sc = (tid & 3) << 3;
  const int mf = lane & 15, kq = lane >> 4;
  const int wm = (wave & 1) << 6, wn = (wave >> 1) << 6;

  const short* Ar0 = A + (size_t)(m0 + sr) * 256 + sc;
  const short* Ar1 = A + (size_t)(m0 + 64 + sr) * 256 + sc;
  const short* Br0 = W + (size_t)(n0 + sr) * 256 + sc;
  const short* Br1 = W + (size_t)(n0 + 64 + sr) * 256 + sc;
  const int wo = wave << 9;

  f32x4 acc[4][4] = {};

  gl_lds16(Ar0, &As[0][wo]);
  gl_lds16(Ar1, &As[0][wo + 2048]);
  gl_lds16(Br0, &Bs[0][wo]);
  gl_lds16(Br1, &Bs[0][wo + 2048]);
  __syncthreads();

  #pragma unroll
  for (int t = 0; t < 8; ++t) {
    const int cur = t & 1;
    if (t < 7) {                       // issue next-tile stage EARLY
      const int kt = (t + 1) << 5;
      gl_lds16(Ar0 + kt, &As[cur ^ 1][wo]);
      gl_lds16(Ar1 + kt, &As[cur ^ 1][wo + 2048]);
      gl_lds16(Br0 + kt, &Bs[cur ^ 1][wo]);
      gl_lds16(Br1 + kt, &Bs[cur ^ 1][wo + 2048]);
    }
    s16x8 af[4], bfr[4];
    #pragma unroll
    for (int i = 0; i < 4; ++i)
      af[i] = *(const s16x8*)&As[cur][((wm + (i << 4) + mf) << 5) + (kq << 3)];
    #pragma unroll
    for (int j = 0; j < 4; ++j)
      bfr[j] = *(const s16x8*)&Bs[cur][((wn + (j << 4) + mf) << 5) + (kq << 3)];
    #pragma unroll
    for (int i = 0; i < 4; ++i)
      #pragma unroll
      for (int j = 0; j < 4; ++j)
        acc[i][j] = __builtin_amdgcn_mfma_f32_16x16x32_bf16(af[i], bfr[j], acc[i][j], 0, 0, 0);
    __syncthreads();
  }

  if (EPI == 0) {
    #pragma unroll
    for (int i = 0; i < 4; ++i) {
      int gm = m0 + wm + (i << 4) + (kq << 2);
      #pragma unroll
      for (int j = 0; j < 4; ++j) {
        int gn = n0 + wn + (j << 4) + mf;
        #pragma unroll
        for (int r = 0; r < 4; ++r)
          Cf[(size_t)(gm + r) * 256 + gn] = acc[i][j][r];
      }
    }
  } else if (EPI == 1) {
    #pragma unroll
    for (int i = 0; i < 4; ++i) {
      int gm = m0 + wm + (i << 4) + (kq << 2);
      #pragma unroll
      for (int j = 0; j < 4; ++j) {
        int gn = n0 + wn + (j << 4) + mf;
        #pragma unroll
        for (int r = 0; r < 4; ++r) {
          int tok = (gm + r) & 8191;
          float v = acc[i][j][r] + ADD[(size_t)tok * 256 + gn];
          Cb[(size_t)(gm + r) * 256 + gn] = f2bf(v);
        }
      }
    }
  } else {
    const int head = m0 >> 13, bb = (m0 >> 12) & 1, lb = m0 & 4095;
    float* obase = Cf + (size_t)head * (2u * 1200u * 4096u) + (size_t)bb * (1200u * 4096u);
    #pragma unroll
    for (int i = 0; i < 4; ++i) {
      int l = lb + wm + (i << 4) + (kq << 2);
      #pragma unroll
      for (int j = 0; j < 4; ++j) {
        int gn = n0 + wn + (j << 4) + mf;
        if (gn < 1200) {
          float bv = bias[gn];
          f32x4 v = acc[i][j];
          v[0] += bv; v[1] += bv; v[2] += bv; v[3] += bv;
          __builtin_nontemporal_store(v, (f32x4*)&obase[(size_t)gn * 4096 + l]);
        }
      }
    }
  }
}

// ---------------------------------------------------------------------------
// K3: FUSED scan: conv1d+SiLU -> xproj -> dtproj -> local scan aggregate ->
// decoupled lookback (agent-scope flags) -> replay + gate. One dispatch
// replaces the old K3/K4/K5 chain; xcg/dblg/Hs round-trips eliminated.
// grid: 1024 = dir(2) x b(2) x ch(256); 256 threads.
// Residency: LDS 35.4KB -> 4 blocks/CU; launch_bounds(256,4) caps VGPR at
// 128 -> all 1024 blocks co-resident; spin-wait is deadlock-free.
// ---------------------------------------------------------------------------
__global__ __launch_bounds__(256, 4) void fused_scan(
    const float* __restrict__ x,
    const float* __restrict__ cw0, const float* __restrict__ cb0,
    const float* __restrict__ cw1, const float* __restrict__ cb1,
    const float* __restrict__ xw0, const float* __restrict__ xw1,
    const float* __restrict__ dtw0, const float* __restrict__ dtb0,
    const float* __restrict__ dtw1, const float* __restrict__ dtb1,
    const float* __restrict__ Alog0, const float* __restrict__ Alog1,
    const float* __restrict__ Dp0, const float* __restrict__ Dp1,
    const float* __restrict__ z,
    float* __restrict__ P, float* __restrict__ Q, float* __restrict__ Pref,
    int* __restrict__ flags, short* __restrict__ yall)
{
  __shared__ float xcs[16 * 256];     // 16 KB
  __shared__ short wxs[256 * 33];     // 16.9 KB, transposed [r][33]
  __shared__ float dls[512];          // 2 KB
  __shared__ int stat;
  const int tid = threadIdx.x;
  const int dir = blockIdx.x >> 9;
  const int b   = (blockIdx.x >> 8) & 1;
  const int ch  = blockIdx.x & 255;
  const int gb  = (dir << 1) | b;
  const int fi  = (gb << 8) + ch;
  const int t0  = ch << 4;
  const float* cw   = dir ? cw1 : cw0;
  const float* cb   = dir ? cb1 : cb0;
  const float* xw   = dir ? xw1 : xw0;
  const float* dtw  = dir ? dtw1 : dtw0;
  const float* dtb  = dir ? dtb1 : dtb0;
  const float* Alog = dir ? Alog1 : Alog0;
  const float* Dp   = dir ? Dp1 : Dp0;
  const size_t xb = ((size_t)b) << 12;
  short* yout = yall + (size_t)dir * (NTOK * 256);

  // --- conv1d + SiLU (depthwise; thread = channel d) ---
  {
    const int d = tid;
    const float w0 = cw[(d << 2)], w1 = cw[(d << 2) + 1],
                w2 = cw[(d << 2) + 2], w3 = cw[(d << 2) + 3];
    const float bias = cb[d];
    float h0 = 0.f, h1 = 0.f, h2 = 0.f;
    #pragma unroll
    for (int i = 0; i < 3; ++i) {
      int ts = t0 - 3 + i; float v = 0.f;
      if (ts >= 0) { int tn = dir ? 4095 - ts : ts; v = x[(xb + tn) * 256 + d]; }
      h0 = h1; h1 = h2; h2 = v;
    }
    #pragma unroll
    for (int s = 0; s < 16; ++s) {
      int ts = t0 + s;
      int tn = dir ? 4095 - ts : ts;
      float xv = x[(xb + tn) * 256 + d];
      float a = bias + w0 * h0 + w1 * h1 + w2 * h2 + w3 * xv;
      h0 = h1; h1 = h2; h2 = xv;
      xcs[s * 256 + d] = a / (1.f + __expf(-a));
    }
  }
  // --- stage xproj weights (bf16, transposed, stride 33) ---
  #pragma unroll
  for (int i = 0; i < 32; ++i) {
    int flat = (i << 8) + tid;          // j = i, r = tid
    wxs[(flat & 255) * 33 + (flat >> 8)] = f2bf(xw[flat]);
  }
  __syncthreads();

  // --- xproj: thread -> (j = tid&31, s0 = tid>>5 and s0+8) ---
  {
    const int j = tid & 31, s0 = tid >> 5;
    float a0 = 0.f, a1 = 0.f;
    #pragma unroll 8
    for (int r = 0; r < 256; ++r) {
      float w = bf2f(wxs[r * 33 + j]);
      a0 = fmaf(xcs[s0 * 256 + r], w, a0);
      a1 = fmaf(xcs[(s0 + 8) * 256 + r], w, a1);
    }
    dls[(s0 << 5) + j] = a0;
    dls[((s0 + 8) << 5) + j] = a1;
  }
  __syncthreads();

  // --- dtproj (softplus) + local scan aggregate (thread = channel d) ---
  const int d = tid;
  float wrow[16];
  #pragma unroll
  for (int r = 0; r < 16; ++r) wrow[r] = dtw[(d << 4) + r];
  const float bias = dtb[d];
  const float Dv = Dp[d];
  float Av[8], p[8], q[8];
  #pragma unroll
  for (int n = 0; n < 8; ++n) {
    Av[n] = -expf(Alog[(d << 3) + n]); p[n] = 1.f; q[n] = 0.f;
  }
  for (int s = 0; s < 16; ++s) {
    float a = bias;
    #pragma unroll
    for (int r = 0; r < 16; ++r) a = fmaf(dls[(s << 5) + r], wrow[r], a);
    float dtv = (a > 20.f) ? a : log1pf(__expf(a));
    float xv = xcs[s * 256 + d];
    float du = dtv * xv;
    #pragma unroll
    for (int n = 0; n < 8; ++n) {
      float dA = __expf(dtv * Av[n]);
      p[n] *= dA;
      q[n] = fmaf(q[n], dA, du * dls[(s << 5) + 16 + n]);
    }
  }

  // --- publish aggregate ---
  const size_t ab = ((size_t)fi << 11) + d;
  #pragma unroll
  for (int n = 0; n < 8; ++n) { P[ab + (n << 8)] = p[n]; Q[ab + (n << 8)] = q[n]; }
  __syncthreads();    // drains vmem: aggregates are in L2 before flag release

  float hin[8];
  if (ch == 0) {
    #pragma unroll
    for (int n = 0; n < 8; ++n) { hin[n] = 0.f; Pref[ab + (n << 8)] = q[n]; }
  } else {
    if (tid == 0)
      __hip_atomic_store(&flags[fi], 1, __ATOMIC_RELEASE, __HIP_MEMORY_SCOPE_AGENT);
    float Pa[8], Qa[8];
    #pragma unroll
    for (int n = 0; n < 8; ++n) { Pa[n] = 1.f; Qa[n] = 0.f; }
    int j = ch - 1;
    for (;;) {
      __syncthreads();
      if (tid == 0) {
        int f;
        for (;;) {
          f = __hip_atomic_load(&flags[(gb << 8) + j], __ATOMIC_RELAXED,
                                __HIP_MEMORY_SCOPE_AGENT);
          if (f >= 1) break;
          __builtin_amdgcn_s_sleep(2);
        }
        // establish acquire ordering for the data reads below
        f = __hip_atomic_load(&flags[(gb << 8) + j], __ATOMIC_ACQUIRE,
                              __HIP_MEMORY_SCOPE_AGENT);
        stat = f;
      }
      __syncthreads();
      const int st = stat;
      const size_t jb = (((size_t)((gb << 8) + j)) << 11) + d;
      if (st == 2) {
        #pragma unroll
        for (int n = 0; n < 8; ++n)
          hin[n] = fmaf(Pa[n], Pref[jb + (n << 8)], Qa[n]);
        break;
      }
      #pragma unroll
      for (int n = 0; n < 8; ++n) {
        float Pj = P[jb + (n << 8)], Qj = Q[jb + (n << 8)];
        Qa[n] = fmaf(Pa[n], Qj, Qa[n]);
        Pa[n] *= Pj;
      }
      --j;
    }
    #pragma unroll
    for (int n = 0; n < 8; ++n) Pref[ab + (n << 8)] = fmaf(p[n], hin[n], q[n]);
  }
  __syncthreads();
  if (tid == 0)
    __hip_atomic_store(&flags[fi], 2, __ATOMIC_RELEASE, __HIP_MEMORY_SCOPE_AGENT);

  // --- replay + D + silu(z) gate ---
  float h[8];
  #pragma unroll
  for (int n = 0; n < 8; ++n) h[n] = hin[n];
  for (int s = 0; s < 16; ++s) {
    float a = bias;
    #pragma unroll
    for (int r = 0; r < 16; ++r) a = fmaf(dls[(s << 5) + r], wrow[r], a);
    float dtv = (a > 20.f) ? a : log1pf(__expf(a));
    int ts = t0 + s;
    float xv = xcs[s * 256 + d];
    float du = dtv * xv;
    float yv = 0.f;
    #pragma unroll
    for (int n = 0; n < 8; ++n) {
      float dA = __expf(dtv * Av[n]);
      h[n] = fmaf(h[n], dA, du * dls[(s << 5) + 16 + n]);
      yv = fmaf(h[n], dls[(s << 5) + 24 + n], yv);
    }
    yv = fmaf(xv, Dv, yv);
    int tn = dir ? (4095 - ts) : ts;
    size_t zi = (xb + tn) * 256 + d;
    float zv = z[zi];
    yout[zi] = f2bf(yv * zv / (1.f + __expf(-zv)));
  }
}

// ---------------------------------------------------------------------------
// K4: EPI1 GEMM with fused RMSNorm of A-rows (replaces rms_all + gemm<1>).
// mode = m0>>13: 0=avg(yf,yb), 1=yf, 2=yb. Pass 1 reproduces rms_all's
// exact reduction order; pass 2 reg-stages rms-scaled bf16 A-chunks to LDS.
// C = bf16(A_rms * Wo^T + seqT skip) -> obuf.  grid (2,192), 256 thr.
// ---------------------------------------------------------------------------
__global__ __launch_bounds__(256) void gemm_rms_epi1(
    const short* __restrict__ yall, const short* __restrict__ W0,
    const float* __restrict__ rmsw, short* __restrict__ Cb,
    const float* __restrict__ ADD)
{
  __shared__ short As[4096];          // [128][32]
  __shared__ short Bs[4096];
  __shared__ float scale[128];
  __shared__ float rw[256];
  const int tid  = threadIdx.x;
  const int lane = tid & 63, wave = tid >> 6;
  const int m0 = blockIdx.y << 7;
  const int n0 = blockIdx.x << 7;
  const int mode = m0 >> 13;
  const int tok0 = m0 & 8191;
  const short* yf = yall;
  const short* yb = yall + 2097152;
  const short* ysel = (mode == 1) ? yf : yb;

  rw[tid] = rmsw[tid];

  // pass 1: per-row sumsq, identical order to old rms_all (wave per row)
  for (int rr = 0; rr < 32; ++rr) {
    int r = (rr << 2) + wave;
    size_t base = (size_t)(tok0 + r) * 256 + (lane << 2);
    float v0, v1, v2, v3;
    if (mode == 0) {
      s16x4 a = *(const s16x4*)&yf[base];
      s16x4 c = *(const s16x4*)&yb[base];
      v0 = 0.5f * (bf2f(a[0]) + bf2f(c[0]));
      v1 = 0.5f * (bf2f(a[1]) + bf2f(c[1]));
      v2 = 0.5f * (bf2f(a[2]) + bf2f(c[2]));
      v3 = 0.5f * (bf2f(a[3]) + bf2f(c[3]));
    } else {
      s16x4 a = *(const s16x4*)&ysel[base];
      v0 = bf2f(a[0]); v1 = bf2f(a[1]); v2 = bf2f(a[2]); v3 = bf2f(a[3]);
    }
    float ss = v0 * v0 + v1 * v1 + v2 * v2 + v3 * v3;
    #pragma unroll
    for (int o = 32; o > 0; o >>= 1) ss += __shfl_xor(ss, o, 64);
    if (lane == 0) scale[r] = rsqrtf(ss * (1.f / 256.f) + 1e-5f);
  }
  __syncthreads();

  const int sr = tid >> 2;
  const int sc = (tid & 3) << 3;
  const int mf = lane & 15, kq = lane >> 4;
  const int wm = (wave & 1) << 6, wn = (wave >> 1) << 6;
  const short* Br0 = W0 + (size_t)(n0 + sr) * 256 + sc;
  const short* Br1 = W0 + (size_t)(n0 + 64 + sr) * 256 + sc;
  const int wo = wave << 9;

  const int ar = tid >> 1;            // A-stage: 2 threads per row
  const int ac = (tid & 1) << 4;      // 16 cols each
  const size_t abase = (size_t)(tok0 + ar) * 256 + ac;
  const float s_r = scale[ar];

  f32x4 acc[4][4] = {};

  for (int t = 0; t < 8; ++t) {
    const int kt = t << 5;
    // stage A chunk: load (L2-hot), rms-scale, round to bf16, ds_write
    {
      s16x8 o0, o1;
      if (mode == 0) {
        s16x8 f0 = *(const s16x8*)&yf[abase + kt];
        s16x8 f1 = *(const s16x8*)&yf[abase + kt + 8];
        s16x8 c0 = *(const s16x8*)&yb[abase + kt];
        s16x8 c1 = *(const s16x8*)&yb[abase + kt + 8];
        #pragma unroll
        for (int e = 0; e < 8; ++e) {
          o0[e] = f2bf((0.5f * (bf2f(f0[e]) + bf2f(c0[e])) * s_r) * rw[kt + ac + e]);
          o1[e] = f2bf((0.5f * (bf2f(f1[e]) + bf2f(c1[e])) * s_r) * rw[kt + ac + 8 + e]);
        }
      } else {
        s16x8 f0 = *(const s16x8*)&ysel[abase + kt];
        s16x8 f1 = *(const s16x8*)&ysel[abase + kt + 8];
        #pragma unroll
        for (int e = 0; e < 8; ++e) {
          o0[e] = f2bf((bf2f(f0[e]) * s_r) * rw[kt + ac + e]);
          o1[e] = f2bf((bf2f(f1[e]) * s_r) * rw[kt + ac + 8 + e]);
        }
      }
      *(s16x8*)&As[(ar << 5) + ac]     = o0;
      *(s16x8*)&As[(ar << 5) + ac + 8] = o1;
    }
    gl_lds16(Br0 + kt, &Bs[wo]);
    gl_lds16(Br1 + kt, &Bs[wo + 2048]);
    __syncthreads();
    s16x8 af[4], bfr[4];
    #pragma unroll
    for (int i = 0; i < 4; ++i)
      af[i] = *(const s16x8*)&As[((wm + (i << 4) + mf) << 5) + (kq << 3)];
    #pragma unroll
    for (int j = 0; j < 4; ++j)
      bfr[j] = *(const s16x8*)&Bs[((wn + (j << 4) + mf) << 5) + (kq << 3)];
    #pragma unroll
    for (int i = 0; i < 4; ++i)
      #pragma unroll
      for (int j = 0; j < 4; ++j)
        acc[i][j] = __builtin_amdgcn_mfma_f32_16x16x32_bf16(af[i], bfr[j], acc[i][j], 0, 0, 0);
    __syncthreads();
  }

  #pragma unroll
  for (int i = 0; i < 4; ++i) {
    int gm = m0 + wm + (i << 4) + (kq << 2);
    #pragma unroll
    for (int j = 0; j < 4; ++j) {
      int gn = n0 + wn + (j << 4) + mf;
      #pragma unroll
      for (int r = 0; r < 4; ++r) {
        int tok = (gm + r) & 8191;
        float v = acc[i][j][r] + ADD[(size_t)tok * 256 + gn];
        Cb[(size_t)(gm + r) * 256 + gn] = f2bf(v);
      }
    }
  }
}

// ---------------------------------------------------------------------------
extern "C" void kernel_launch(void* const* d_in, const int* in_sizes, int n_in,
                              void* d_out, int out_size, void* d_ws, size_t ws_size,
                              hipStream_t stream) {
  const float* in0        = (const float*)d_in[0];
  const float* in1        = (const float*)d_in[1];
  const float* n0w        = (const float*)d_in[2];
  const float* n0b        = (const float*)d_in[3];
  const float* n1w        = (const float*)d_in[4];
  const float* n1b        = (const float*)d_in[5];
  const float* in_proj_w  = (const float*)d_in[6];
  const float* in_projz_w = (const float*)d_in[7];
  const float* conv1d_w   = (const float*)d_in[8];
  const float* conv1d_b   = (const float*)d_in[9];
  const float* conv1db_w  = (const float*)d_in[10];
  const float* conv1db_b  = (const float*)d_in[11];
  const float* xproj_w    = (const float*)d_in[12];
  const float* xprojb_w   = (const float*)d_in[13];
  const float* dtproj_w   = (const float*)d_in[14];
  const float* dtproj_b   = (const float*)d_in[15];
  const float* dtprojb_w  = (const float*)d_in[16];
  const float* dtprojb_b  = (const float*)d_in[17];
  const float* A_log      = (const float*)d_in[18];
  const float* Ab_log     = (const float*)d_in[19];
  const float* D_p        = (const float*)d_in[20];
  const float* D_b        = (const float*)d_in[21];
  const float* rms_w      = (const float*)d_in[22];
  const float* out_proj_w = (const float*)d_in[23];
  const float* conv3d_w   = (const float*)d_in[24];
  const float* conv3d_b   = (const float*)d_in[25];
  (void)in_sizes; (void)n_in; (void)out_size; (void)ws_size;

  float* ws = (float*)d_ws;
  size_t o = 0;
  short* xlnz = (short*)(ws + o); o += 2097152;   // 16384x256 bf16
  float* seqT = ws + o;           o += 2097152;
  float* x    = ws + o;           o += 2097152;   // x then z contiguous
  float* z    = ws + o;           o += 2097152;
  float* P    = ws + o;           o += 2097152;   // 4 gb x 256 ch x 2048
  float* Q    = ws + o;           o += 2097152;
  float* Pref = ws + o;           o += 2097152;
  short* yall = (short*)(ws + o); o += 2097152;   // 2 dirs x 8192x256 bf16
  short* obuf = (short*)(ws + o); o += 3145728;
  short* Wx   = (short*)(ws + o); o += 32768;
  short* Wz   = (short*)(ws + o); o += 32768;
  short* Wo   = (short*)(ws + o); o += 32768;
  short* Wc   = (short*)(ws + o); o += 163840;    // 1280x256 bf16 padded
  int*   flags = (int*)(ws + o);  o += 1024;
  float* out  = (float*)d_out;

  dim3 blk(256);

  ln_transpose_kernel<<<dim3(512), blk, 0, stream>>>(
      in0, in1, n0w, n0b, n1w, n1b,
      in_proj_w, in_projz_w, out_proj_w, conv3d_w, Wx, Wz, Wo, Wc,
      xlnz, seqT, flags);

  // in_proj: x|z batched (M=16384, weight switch at 8192)
  gemm_fast<0><<<dim3(2, 128), blk, 0, stream>>>(xlnz, Wx, Wz, x, nullptr, nullptr, nullptr, 8192);

  // both directions: conv+silu -> xproj -> dtproj -> full scan -> gate
  fused_scan<<<dim3(1024), blk, 0, stream>>>(
      x, conv1d_w, conv1d_b, conv1db_w, conv1db_b,
      xproj_w, xprojb_w, dtproj_w, dtproj_b, dtprojb_w, dtprojb_b,
      A_log, Ab_log, D_p, D_b, z, P, Q, Pref, flags, yall);

  // heads: rms fused into out_proj+skip (batched) -> conv3d (batched)
  gemm_rms_epi1<<<dim3(2, 192), blk, 0, stream>>>(yall, Wo, rms_w, obuf, seqT);
  gemm_fast<2><<<dim3(10, 192), blk, 0, stream>>>(obuf, Wc, nullptr, out, nullptr, nullptr, conv3d_b, 0);
}

// Round 5
// 424.441 us; speedup vs baseline: 1.1883x; 1.1883x over previous
//
#include <hip/hip_runtime.h>
#include <cstdint>

#define NTOK 8192

typedef __attribute__((ext_vector_type(4))) float f32x4;
typedef __attribute__((ext_vector_type(8))) short s16x8;
typedef __attribute__((ext_vector_type(4))) short s16x4;

__device__ __forceinline__ short f2bf(float f) {
  union { float f; unsigned u; } x; x.f = f;
  unsigned r = x.u + 0x7FFFu + ((x.u >> 16) & 1u);
  return (short)(r >> 16);
}
__device__ __forceinline__ float bf2f(short s) {
  union { float f; unsigned u; } x;
  x.u = ((unsigned)(unsigned short)s) << 16;
  return x.f;
}
__device__ __forceinline__ void gl_lds16(const void* g, void* l) {
  __builtin_amdgcn_global_load_lds((const unsigned int*)g, (unsigned int*)l, 16, 0, 0);
}

// ---------------------------------------------------------------------------
// K1: transpose (B,DIM,L)->(B,L,DIM) + LayerNorm both inputs (bf16 out),
// seqT f32; converts 4 big weight matrices to bf16; block 0 zeroes the
// sync flags for fused_scan (agent-scope stores, stream-ordered before it).
// grid: 512 blocks, 256 threads
// ---------------------------------------------------------------------------
__global__ __launch_bounds__(256) void ln_transpose_kernel(
    const float* __restrict__ in0, const float* __restrict__ in1,
    const float* __restrict__ w0, const float* __restrict__ b0,
    const float* __restrict__ w1, const float* __restrict__ b1,
    const float* __restrict__ wxp, const float* __restrict__ wzp,
    const float* __restrict__ wop, const float* __restrict__ wcp,
    short* __restrict__ Wx, short* __restrict__ Wz,
    short* __restrict__ Wo, short* __restrict__ Wc,
    short* __restrict__ xlnz, float* __restrict__ seqT,
    int* __restrict__ flags)
{
  __shared__ float tile[32 * 257];
  __shared__ float mu[32], rs[32];
  const int tid  = threadIdx.x;
  const int pass = blockIdx.x >> 8;
  const int b    = (blockIdx.x >> 7) & 1;
  const int l0   = (blockIdx.x & 127) << 5;

  if (blockIdx.x == 0) {
    #pragma unroll
    for (int i = 0; i < 4; ++i)
      __hip_atomic_store(&flags[(i << 8) + tid], 0, __ATOMIC_RELAXED,
                         __HIP_MEMORY_SCOPE_AGENT);
  }

  // weight conversion: 1024 elements per block (512*1024 = 524288 total)
  {
    int base = (int)blockIdx.x << 10;
    #pragma unroll
    for (int i = 0; i < 4; ++i) {
      int idx = base + (i << 8) + tid;
      if (idx < 65536)       Wx[idx] = f2bf(wxp[idx]);
      else if (idx < 131072) Wz[idx - 65536] = f2bf(wzp[idx - 65536]);
      else if (idx < 196608) Wo[idx - 131072] = f2bf(wop[idx - 131072]);
      else {
        int k = idx - 196608;            // 1280x256 padded
        Wc[k] = ((k >> 8) < 1200) ? f2bf(wcp[k]) : (short)0;
      }
    }
  }

  const float* in = pass ? in1 : in0;
  #pragma unroll 8
  for (int i = 0; i < 32; ++i) {
    int e = (i << 8) + tid;
    int c = e >> 5, lo = e & 31;
    tile[lo * 257 + c] = in[((size_t)(b * 256 + c) << 12) + l0 + lo];
  }
  __syncthreads();
  if (tid < 64) {               // one wave: 32 rows x 2 halves (order-preserving)
    int r = tid & 31, hh = tid >> 5;
    float s = 0.f, ss = 0.f;
    #pragma unroll 16
    for (int c = hh * 128; c < hh * 128 + 128; ++c) {
      float v = tile[r * 257 + c];
      s += v; ss += v * v;
    }
    s  += __shfl_xor(s, 32, 64);
    ss += __shfl_xor(ss, 32, 64);
    if (hh == 0) {
      float m = s * (1.f / 256.f);
      mu[r] = m;
      rs[r] = rsqrtf(ss * (1.f / 256.f) - m * m + 1e-5f);
    }
  }
  __syncthreads();
  const float* w  = pass ? w1 : w0;
  const float* bb = pass ? b1 : b0;
  float wv = w[tid], bv = bb[tid];
  #pragma unroll 8
  for (int i = 0; i < 32; ++i) {
    float v = tile[i * 257 + tid];
    int row = (pass ? 8192 : 0) + (b << 12) + l0 + i;
    xlnz[(size_t)row * 256 + tid] = f2bf((v - mu[i]) * rs[i] * wv + bv);
    if (pass == 0) seqT[(((size_t)b << 12) + l0 + i) * 256 + tid] = v;
  }
}

// ---------------------------------------------------------------------------
// K2: fast 128x128 bf16 MFMA GEMM, C[M,N] = A[M,256] * W[N,256]^T
// Double-buffered LDS, single barrier per K-step.
// EPI 0: f32 store N=256; W switches W0->W1 at m>=Msplit (in_proj x|z)
// EPI 2: conv3d: transposed nontemporal f32x4 store + bias[n]
// ---------------------------------------------------------------------------
template <int EPI>
__global__ __launch_bounds__(256) void gemm_fast(
    const short* __restrict__ A, const short* __restrict__ W0,
    const short* __restrict__ W1, float* __restrict__ Cf,
    short* __restrict__ Cb, const float* __restrict__ ADD,
    const float* __restrict__ bias, int Msplit)
{
  __shared__ short As[2][4096];   // [buf][128][32] bf16 (global_load_lds layout)
  __shared__ short Bs[2][4096];
  const int tid  = threadIdx.x;
  const int lane = tid & 63, wave = tid >> 6;
  const int m0 = blockIdx.y << 7;
  const int n0 = blockIdx.x << 7;
  const short* W = (EPI == 0 && m0 >= Msplit) ? W1 : W0;

  const int sr = tid >> 2;
  const int sc = (tid & 3) << 3;
  const int mf = lane & 15, kq = lane >> 4;
  const int wm = (wave & 1) << 6, wn = (wave >> 1) << 6;

  const short* Ar0 = A + (size_t)(m0 + sr) * 256 + sc;
  const short* Ar1 = A + (size_t)(m0 + 64 + sr) * 256 + sc;
  const short* Br0 = W + (size_t)(n0 + sr) * 256 + sc;
  const short* Br1 = W + (size_t)(n0 + 64 + sr) * 256 + sc;
  const int wo = wave << 9;

  f32x4 acc[4][4] = {};

  gl_lds16(Ar0, &As[0][wo]);
  gl_lds16(Ar1, &As[0][wo + 2048]);
  gl_lds16(Br0, &Bs[0][wo]);
  gl_lds16(Br1, &Bs[0][wo + 2048]);
  __syncthreads();

  #pragma unroll
  for (int t = 0; t < 8; ++t) {
    const int cur = t & 1;
    if (t < 7) {                       // issue next-tile stage EARLY
      const int kt = (t + 1) << 5;
      gl_lds16(Ar0 + kt, &As[cur ^ 1][wo]);
      gl_lds16(Ar1 + kt, &As[cur ^ 1][wo + 2048]);
      gl_lds16(Br0 + kt, &Bs[cur ^ 1][wo]);
      gl_lds16(Br1 + kt, &Bs[cur ^ 1][wo + 2048]);
    }
    s16x8 af[4], bfr[4];
    #pragma unroll
    for (int i = 0; i < 4; ++i)
      af[i] = *(const s16x8*)&As[cur][((wm + (i << 4) + mf) << 5) + (kq << 3)];
    #pragma unroll
    for (int j = 0; j < 4; ++j)
      bfr[j] = *(const s16x8*)&Bs[cur][((wn + (j << 4) + mf) << 5) + (kq << 3)];
    #pragma unroll
    for (int i = 0; i < 4; ++i)
      #pragma unroll
      for (int j = 0; j < 4; ++j)
        acc[i][j] = __builtin_amdgcn_mfma_f32_16x16x32_bf16(af[i], bfr[j], acc[i][j], 0, 0, 0);
    __syncthreads();
  }

  if (EPI == 0) {
    #pragma unroll
    for (int i = 0; i < 4; ++i) {
      int gm = m0 + wm + (i << 4) + (kq << 2);
      #pragma unroll
      for (int j = 0; j < 4; ++j) {
        int gn = n0 + wn + (j << 4) + mf;
        #pragma unroll
        for (int r = 0; r < 4; ++r)
          Cf[(size_t)(gm + r) * 256 + gn] = acc[i][j][r];
      }
    }
  } else if (EPI == 1) {
    #pragma unroll
    for (int i = 0; i < 4; ++i) {
      int gm = m0 + wm + (i << 4) + (kq << 2);
      #pragma unroll
      for (int j = 0; j < 4; ++j) {
        int gn = n0 + wn + (j << 4) + mf;
        #pragma unroll
        for (int r = 0; r < 4; ++r) {
          int tok = (gm + r) & 8191;
          float v = acc[i][j][r] + ADD[(size_t)tok * 256 + gn];
          Cb[(size_t)(gm + r) * 256 + gn] = f2bf(v);
        }
      }
    }
  } else {
    const int head = m0 >> 13, bb = (m0 >> 12) & 1, lb = m0 & 4095;
    float* obase = Cf + (size_t)head * (2u * 1200u * 4096u) + (size_t)bb * (1200u * 4096u);
    #pragma unroll
    for (int i = 0; i < 4; ++i) {
      int l = lb + wm + (i << 4) + (kq << 2);
      #pragma unroll
      for (int j = 0; j < 4; ++j) {
        int gn = n0 + wn + (j << 4) + mf;
        if (gn < 1200) {
          float bv = bias[gn];
          f32x4 v = acc[i][j];
          v[0] += bv; v[1] += bv; v[2] += bv; v[3] += bv;
          __builtin_nontemporal_store(v, (f32x4*)&obase[(size_t)gn * 4096 + l]);
        }
      }
    }
  }
}

// ---------------------------------------------------------------------------
// K3: FUSED scan v2: conv1d+SiLU -> xproj -> dtproj -> local aggregate ->
// BULK sync (per-gb arrival counter) -> 8 chain-blocks/gb run the
// inter-chunk scan fully d-parallel -> chain flags -> replay + gate.
// No per-chunk lookback (round-4 lesson: 255 serial hops x ~1us = 253us).
// grid: 1024 = dir(2) x b(2) x ch(256); 256 threads.
// Residency (required: early blocks wait on late arrivals): LDS 35.4KB ->
// 4 blocks/CU; launch_bounds(256,4) caps VGPR<=128 (measured 52) ->
// 4x256 = 1024 co-resident = grid. Spins are BOUNDED: on timeout we
// proceed (wrong output, kernel terminates -> diagnosable, no hang).
// flags[]: [0..3] per-gb arrival counters; [16+gb*8+n] chain-done flags.
// ---------------------------------------------------------------------------
__global__ __launch_bounds__(256, 4) void fused_scan(
    const float* __restrict__ x,
    const float* __restrict__ cw0, const float* __restrict__ cb0,
    const float* __restrict__ cw1, const float* __restrict__ cb1,
    const float* __restrict__ xw0, const float* __restrict__ xw1,
    const float* __restrict__ dtw0, const float* __restrict__ dtb0,
    const float* __restrict__ dtw1, const float* __restrict__ dtb1,
    const float* __restrict__ Alog0, const float* __restrict__ Alog1,
    const float* __restrict__ Dp0, const float* __restrict__ Dp1,
    const float* __restrict__ z,
    float* __restrict__ P, float* __restrict__ Q, float* __restrict__ Hs,
    int* __restrict__ flags, short* __restrict__ yall)
{
  __shared__ float xcs[16 * 256];     // 16 KB
  __shared__ short wxs[256 * 33];     // 16.9 KB, transposed [r][33]
  __shared__ float dls[512];          // 2 KB
  const int tid = threadIdx.x;
  const int dir = blockIdx.x >> 9;
  const int b   = (blockIdx.x >> 8) & 1;
  const int ch  = blockIdx.x & 255;
  const int gb  = (dir << 1) | b;
  const int fi  = (gb << 8) + ch;
  const int t0  = ch << 4;
  const float* cw   = dir ? cw1 : cw0;
  const float* cb   = dir ? cb1 : cb0;
  const float* xw   = dir ? xw1 : xw0;
  const float* dtw  = dir ? dtw1 : dtw0;
  const float* dtb  = dir ? dtb1 : dtb0;
  const float* Alog = dir ? Alog1 : Alog0;
  const float* Dp   = dir ? Dp1 : Dp0;
  const size_t xb = ((size_t)b) << 12;
  short* yout = yall + (size_t)dir * (NTOK * 256);

  // --- conv1d + SiLU (depthwise; thread = channel d) ---
  {
    const int d = tid;
    const float w0 = cw[(d << 2)], w1 = cw[(d << 2) + 1],
                w2 = cw[(d << 2) + 2], w3 = cw[(d << 2) + 3];
    const float bias = cb[d];
    float h0 = 0.f, h1 = 0.f, h2 = 0.f;
    #pragma unroll
    for (int i = 0; i < 3; ++i) {
      int ts = t0 - 3 + i; float v = 0.f;
      if (ts >= 0) { int tn = dir ? 4095 - ts : ts; v = x[(xb + tn) * 256 + d]; }
      h0 = h1; h1 = h2; h2 = v;
    }
    #pragma unroll
    for (int s = 0; s < 16; ++s) {
      int ts = t0 + s;
      int tn = dir ? 4095 - ts : ts;
      float xv = x[(xb + tn) * 256 + d];
      float a = bias + w0 * h0 + w1 * h1 + w2 * h2 + w3 * xv;
      h0 = h1; h1 = h2; h2 = xv;
      xcs[s * 256 + d] = a / (1.f + __expf(-a));
    }
  }
  // --- stage xproj weights (bf16, transposed, stride 33) ---
  #pragma unroll
  for (int i = 0; i < 32; ++i) {
    int flat = (i << 8) + tid;          // j = i, r = tid
    wxs[(flat & 255) * 33 + (flat >> 8)] = f2bf(xw[flat]);
  }
  __syncthreads();

  // --- xproj: thread -> (j = tid&31, s0 = tid>>5 and s0+8) ---
  {
    const int j = tid & 31, s0 = tid >> 5;
    float a0 = 0.f, a1 = 0.f;
    #pragma unroll 8
    for (int r = 0; r < 256; ++r) {
      float w = bf2f(wxs[r * 33 + j]);
      a0 = fmaf(xcs[s0 * 256 + r], w, a0);
      a1 = fmaf(xcs[(s0 + 8) * 256 + r], w, a1);
    }
    dls[(s0 << 5) + j] = a0;
    dls[((s0 + 8) << 5) + j] = a1;
  }
  __syncthreads();

  // --- dtproj (softplus) + local scan aggregate (thread = channel d) ---
  const int d = tid;
  float wrow[16];
  #pragma unroll
  for (int r = 0; r < 16; ++r) wrow[r] = dtw[(d << 4) + r];
  const float bias = dtb[d];
  const float Dv = Dp[d];
  float Av[8], p[8], q[8];
  #pragma unroll
  for (int n = 0; n < 8; ++n) {
    Av[n] = -expf(Alog[(d << 3) + n]); p[n] = 1.f; q[n] = 0.f;
  }
  for (int s = 0; s < 16; ++s) {
    float a = bias;
    #pragma unroll
    for (int r = 0; r < 16; ++r) a = fmaf(dls[(s << 5) + r], wrow[r], a);
    float dtv = (a > 20.f) ? a : log1pf(__expf(a));
    float xv = xcs[s * 256 + d];
    float du = dtv * xv;
    #pragma unroll
    for (int n = 0; n < 8; ++n) {
      float dA = __expf(dtv * Av[n]);
      p[n] *= dA;
      q[n] = fmaf(q[n], dA, du * dls[(s << 5) + 16 + n]);
    }
  }

  // --- publish aggregate, arrive at per-gb counter ---
  const size_t ab = ((size_t)fi << 11) + d;
  #pragma unroll
  for (int n = 0; n < 8; ++n) { P[ab + (n << 8)] = p[n]; Q[ab + (n << 8)] = q[n]; }
  __syncthreads();    // drains vmem: P,Q complete before the release below
  if (tid == 0)
    __hip_atomic_fetch_add(&flags[gb], 1, __ATOMIC_RELEASE, __HIP_MEMORY_SCOPE_AGENT);

  // --- chain executors: ch<8 handles state n=ch, fully d-parallel ---
  if (ch < 8) {
    if (tid == 0) {
      for (int it = 0; it < (1 << 18); ++it) {
        if (__hip_atomic_load(&flags[gb], __ATOMIC_RELAXED,
                              __HIP_MEMORY_SCOPE_AGENT) >= 256) break;
        __builtin_amdgcn_s_sleep(2);
      }
      (void)__hip_atomic_load(&flags[gb], __ATOMIC_ACQUIRE,
                              __HIP_MEMORY_SCOPE_AGENT);
    }
    __syncthreads();
    const size_t cb0i = (((size_t)(gb << 8)) << 11) + (ch << 8) + tid;
    float hh = 0.f;
    #pragma unroll 8
    for (int chk = 0; chk < 256; ++chk) {
      size_t i = cb0i + ((size_t)chk << 11);
      Hs[i] = hh;                       // exclusive prefix (matches scan_p2)
      hh = fmaf(P[i], hh, Q[i]);
    }
    __syncthreads();    // drain Hs stores before release
    if (tid == 0)
      __hip_atomic_store(&flags[16 + (gb << 3) + ch], 1, __ATOMIC_RELEASE,
                         __HIP_MEMORY_SCOPE_AGENT);
  }

  // --- wait for all 8 chains of this gb ---
  if (tid == 0) {
    for (int n = 0; n < 8; ++n) {
      for (int it = 0; it < (1 << 18); ++it) {
        if (__hip_atomic_load(&flags[16 + (gb << 3) + n], __ATOMIC_RELAXED,
                              __HIP_MEMORY_SCOPE_AGENT) != 0) break;
        __builtin_amdgcn_s_sleep(2);
      }
    }
    (void)__hip_atomic_load(&flags[16 + (gb << 3) + 7], __ATOMIC_ACQUIRE,
                            __HIP_MEMORY_SCOPE_AGENT);
  }
  __syncthreads();

  // --- replay + D + silu(z) gate ---
  float h[8];
  #pragma unroll
  for (int n = 0; n < 8; ++n) h[n] = Hs[ab + (n << 8)];
  for (int s = 0; s < 16; ++s) {
    float a = bias;
    #pragma unroll
    for (int r = 0; r < 16; ++r) a = fmaf(dls[(s << 5) + r], wrow[r], a);
    float dtv = (a > 20.f) ? a : log1pf(__expf(a));
    int ts = t0 + s;
    float xv = xcs[s * 256 + d];
    float du = dtv * xv;
    float yv = 0.f;
    #pragma unroll
    for (int n = 0; n < 8; ++n) {
      float dA = __expf(dtv * Av[n]);
      h[n] = fmaf(h[n], dA, du * dls[(s << 5) + 16 + n]);
      yv = fmaf(h[n], dls[(s << 5) + 24 + n], yv);
    }
    yv = fmaf(xv, Dv, yv);
    int tn = dir ? (4095 - ts) : ts;
    size_t zi = (xb + tn) * 256 + d;
    float zv = z[zi];
    yout[zi] = f2bf(yv * zv / (1.f + __expf(-zv)));
  }
}

// ---------------------------------------------------------------------------
// K4: EPI1 GEMM with fused RMSNorm of A-rows (replaces rms_all + gemm<1>).
// mode = m0>>13: 0=avg(yf,yb), 1=yf, 2=yb. Pass 1 reproduces rms_all's
// exact reduction order; pass 2 reg-stages rms-scaled bf16 A-chunks to LDS.
// C = bf16(A_rms * Wo^T + seqT skip) -> obuf.  grid (2,192), 256 thr.
// ---------------------------------------------------------------------------
__global__ __launch_bounds__(256) void gemm_rms_epi1(
    const short* __restrict__ yall, const short* __restrict__ W0,
    const float* __restrict__ rmsw, short* __restrict__ Cb,
    const float* __restrict__ ADD)
{
  __shared__ short As[4096];          // [128][32]
  __shared__ short Bs[4096];
  __shared__ float scale[128];
  __shared__ float rw[256];
  const int tid  = threadIdx.x;
  const int lane = tid & 63, wave = tid >> 6;
  const int m0 = blockIdx.y << 7;
  const int n0 = blockIdx.x << 7;
  const int mode = m0 >> 13;
  const int tok0 = m0 & 8191;
  const short* yf = yall;
  const short* yb = yall + 2097152;
  const short* ysel = (mode == 1) ? yf : yb;

  rw[tid] = rmsw[tid];

  // pass 1: per-row sumsq, identical order to old rms_all (wave per row)
  for (int rr = 0; rr < 32; ++rr) {
    int r = (rr << 2) + wave;
    size_t base = (size_t)(tok0 + r) * 256 + (lane << 2);
    float v0, v1, v2, v3;
    if (mode == 0) {
      s16x4 a = *(const s16x4*)&yf[base];
      s16x4 c = *(const s16x4*)&yb[base];
      v0 = 0.5f * (bf2f(a[0]) + bf2f(c[0]));
      v1 = 0.5f * (bf2f(a[1]) + bf2f(c[1]));
      v2 = 0.5f * (bf2f(a[2]) + bf2f(c[2]));
      v3 = 0.5f * (bf2f(a[3]) + bf2f(c[3]));
    } else {
      s16x4 a = *(const s16x4*)&ysel[base];
      v0 = bf2f(a[0]); v1 = bf2f(a[1]); v2 = bf2f(a[2]); v3 = bf2f(a[3]);
    }
    float ss = v0 * v0 + v1 * v1 + v2 * v2 + v3 * v3;
    #pragma unroll
    for (int o = 32; o > 0; o >>= 1) ss += __shfl_xor(ss, o, 64);
    if (lane == 0) scale[r] = rsqrtf(ss * (1.f / 256.f) + 1e-5f);
  }
  __syncthreads();

  const int sr = tid >> 2;
  const int sc = (tid & 3) << 3;
  const int mf = lane & 15, kq = lane >> 4;
  const int wm = (wave & 1) << 6, wn = (wave >> 1) << 6;
  const short* Br0 = W0 + (size_t)(n0 + sr) * 256 + sc;
  const short* Br1 = W0 + (size_t)(n0 + 64 + sr) * 256 + sc;
  const int wo = wave << 9;

  const int ar = tid >> 1;            // A-stage: 2 threads per row
  const int ac = (tid & 1) << 4;      // 16 cols each
  const size_t abase = (size_t)(tok0 + ar) * 256 + ac;
  const float s_r = scale[ar];

  f32x4 acc[4][4] = {};

  for (int t = 0; t < 8; ++t) {
    const int kt = t << 5;
    // stage A chunk: load (L2-hot), rms-scale, round to bf16, ds_write
    {
      s16x8 o0, o1;
      if (mode == 0) {
        s16x8 f0 = *(const s16x8*)&yf[abase + kt];
        s16x8 f1 = *(const s16x8*)&yf[abase + kt + 8];
        s16x8 c0 = *(const s16x8*)&yb[abase + kt];
        s16x8 c1 = *(const s16x8*)&yb[abase + kt + 8];
        #pragma unroll
        for (int e = 0; e < 8; ++e) {
          o0[e] = f2bf((0.5f * (bf2f(f0[e]) + bf2f(c0[e])) * s_r) * rw[kt + ac + e]);
          o1[e] = f2bf((0.5f * (bf2f(f1[e]) + bf2f(c1[e])) * s_r) * rw[kt + ac + 8 + e]);
        }
      } else {
        s16x8 f0 = *(const s16x8*)&ysel[abase + kt];
        s16x8 f1 = *(const s16x8*)&ysel[abase + kt + 8];
        #pragma unroll
        for (int e = 0; e < 8; ++e) {
          o0[e] = f2bf((bf2f(f0[e]) * s_r) * rw[kt + ac + e]);
          o1[e] = f2bf((bf2f(f1[e]) * s_r) * rw[kt + ac + 8 + e]);
        }
      }
      *(s16x8*)&As[(ar << 5) + ac]     = o0;
      *(s16x8*)&As[(ar << 5) + ac + 8] = o1;
    }
    gl_lds16(Br0 + kt, &Bs[wo]);
    gl_lds16(Br1 + kt, &Bs[wo + 2048]);
    __syncthreads();
    s16x8 af[4], bfr[4];
    #pragma unroll
    for (int i = 0; i < 4; ++i)
      af[i] = *(const s16x8*)&As[((wm + (i << 4) + mf) << 5) + (kq << 3)];
    #pragma unroll
    for (int j = 0; j < 4; ++j)
      bfr[j] = *(const s16x8*)&Bs[((wn + (j << 4) + mf) << 5) + (kq << 3)];
    #pragma unroll
    for (int i = 0; i < 4; ++i)
      #pragma unroll
      for (int j = 0; j < 4; ++j)
        acc[i][j] = __builtin_amdgcn_mfma_f32_16x16x32_bf16(af[i], bfr[j], acc[i][j], 0, 0, 0);
    __syncthreads();
  }

  #pragma unroll
  for (int i = 0; i < 4; ++i) {
    int gm = m0 + wm + (i << 4) + (kq << 2);
    #pragma unroll
    for (int j = 0; j < 4; ++j) {
      int gn = n0 + wn + (j << 4) + mf;
      #pragma unroll
      for (int r = 0; r < 4; ++r) {
        int tok = (gm + r) & 8191;
        float v = acc[i][j][r] + ADD[(size_t)tok * 256 + gn];
        Cb[(size_t)(gm + r) * 256 + gn] = f2bf(v);
      }
    }
  }
}

// ---------------------------------------------------------------------------
extern "C" void kernel_launch(void* const* d_in, const int* in_sizes, int n_in,
                              void* d_out, int out_size, void* d_ws, size_t ws_size,
                              hipStream_t stream) {
  const float* in0        = (const float*)d_in[0];
  const float* in1        = (const float*)d_in[1];
  const float* n0w        = (const float*)d_in[2];
  const float* n0b        = (const float*)d_in[3];
  const float* n1w        = (const float*)d_in[4];
  const float* n1b        = (const float*)d_in[5];
  const float* in_proj_w  = (const float*)d_in[6];
  const float* in_projz_w = (const float*)d_in[7];
  const float* conv1d_w   = (const float*)d_in[8];
  const float* conv1d_b   = (const float*)d_in[9];
  const float* conv1db_w  = (const float*)d_in[10];
  const float* conv1db_b  = (const float*)d_in[11];
  const float* xproj_w    = (const float*)d_in[12];
  const float* xprojb_w   = (const float*)d_in[13];
  const float* dtproj_w   = (const float*)d_in[14];
  const float* dtproj_b   = (const float*)d_in[15];
  const float* dtprojb_w  = (const float*)d_in[16];
  const float* dtprojb_b  = (const float*)d_in[17];
  const float* A_log      = (const float*)d_in[18];
  const float* Ab_log     = (const float*)d_in[19];
  const float* D_p        = (const float*)d_in[20];
  const float* D_b        = (const float*)d_in[21];
  const float* rms_w      = (const float*)d_in[22];
  const float* out_proj_w = (const float*)d_in[23];
  const float* conv3d_w   = (const float*)d_in[24];
  const float* conv3d_b   = (const float*)d_in[25];
  (void)in_sizes; (void)n_in; (void)out_size; (void)ws_size;

  float* ws = (float*)d_ws;
  size_t o = 0;
  short* xlnz = (short*)(ws + o); o += 2097152;   // 16384x256 bf16
  float* seqT = ws + o;           o += 2097152;
  float* x    = ws + o;           o += 2097152;   // x then z contiguous
  float* z    = ws + o;           o += 2097152;
  float* P    = ws + o;           o += 2097152;   // 4 gb x 256 ch x 2048
  float* Q    = ws + o;           o += 2097152;
  float* Hs   = ws + o;           o += 2097152;
  short* yall = (short*)(ws + o); o += 2097152;   // 2 dirs x 8192x256 bf16
  short* obuf = (short*)(ws + o); o += 3145728;
  short* Wx   = (short*)(ws + o); o += 32768;
  short* Wz   = (short*)(ws + o); o += 32768;
  short* Wo   = (short*)(ws + o); o += 32768;
  short* Wc   = (short*)(ws + o); o += 163840;    // 1280x256 bf16 padded
  int*   flags = (int*)(ws + o);  o += 1024;
  float* out  = (float*)d_out;

  dim3 blk(256);

  ln_transpose_kernel<<<dim3(512), blk, 0, stream>>>(
      in0, in1, n0w, n0b, n1w, n1b,
      in_proj_w, in_projz_w, out_proj_w, conv3d_w, Wx, Wz, Wo, Wc,
      xlnz, seqT, flags);

  // in_proj: x|z batched (M=16384, weight switch at 8192)
  gemm_fast<0><<<dim3(2, 128), blk, 0, stream>>>(xlnz, Wx, Wz, x, nullptr, nullptr, nullptr, 8192);

  // both directions: conv+silu -> xproj -> dtproj -> full scan -> gate
  fused_scan<<<dim3(1024), blk, 0, stream>>>(
      x, conv1d_w, conv1d_b, conv1db_w, conv1db_b,
      xproj_w, xprojb_w, dtproj_w, dtproj_b, dtprojb_w, dtprojb_b,
      A_log, Ab_log, D_p, D_b, z, P, Q, Hs, flags, yall);

  // heads: rms fused into out_proj+skip (batched) -> conv3d (batched)
  gemm_rms_epi1<<<dim3(2, 192), blk, 0, stream>>>(yall, Wo, rms_w, obuf, seqT);
  gemm_fast<2><<<dim3(10, 192), blk, 0, stream>>>(obuf, Wc, nullptr, out, nullptr, nullptr, conv3d_b, 0);
}

// Round 6
// 345.547 us; speedup vs baseline: 1.4596x; 1.2283x over previous
//
#include <hip/hip_runtime.h>
#include <cstdint>

#define NTOK 8192

typedef __attribute__((ext_vector_type(4))) float f32x4;
typedef __attribute__((ext_vector_type(8))) short s16x8;
typedef __attribute__((ext_vector_type(4))) short s16x4;

__device__ __forceinline__ short f2bf(float f) {
  union { float f; unsigned u; } x; x.f = f;
  unsigned r = x.u + 0x7FFFu + ((x.u >> 16) & 1u);
  return (short)(r >> 16);
}
__device__ __forceinline__ float bf2f(short s) {
  union { float f; unsigned u; } x;
  x.u = ((unsigned)(unsigned short)s) << 16;
  return x.f;
}
__device__ __forceinline__ void gl_lds16(const void* g, void* l) {
  __builtin_amdgcn_global_load_lds((const unsigned int*)g, (unsigned int*)l, 16, 0, 0);
}

// ---------------------------------------------------------------------------
// K1: transpose (B,DIM,L)->(B,L,DIM) + LayerNorm both inputs (bf16 out);
// converts the 4 big weight matrices to bf16. (seqT eliminated: skip-add
// now reads in0 directly in gemm_rms_epi1.)
// grid: 512 blocks, 256 threads
// ---------------------------------------------------------------------------
__global__ __launch_bounds__(256) void ln_transpose_kernel(
    const float* __restrict__ in0, const float* __restrict__ in1,
    const float* __restrict__ w0, const float* __restrict__ b0,
    const float* __restrict__ w1, const float* __restrict__ b1,
    const float* __restrict__ wxp, const float* __restrict__ wzp,
    const float* __restrict__ wop, const float* __restrict__ wcp,
    short* __restrict__ Wx, short* __restrict__ Wz,
    short* __restrict__ Wo, short* __restrict__ Wc,
    short* __restrict__ xlnz)
{
  __shared__ float tile[32 * 257];
  __shared__ float mu[32], rs[32];
  const int tid  = threadIdx.x;
  const int pass = blockIdx.x >> 8;
  const int b    = (blockIdx.x >> 7) & 1;
  const int l0   = (blockIdx.x & 127) << 5;

  // weight conversion: 1024 elements per block (512*1024 = 524288 total)
  {
    int base = (int)blockIdx.x << 10;
    #pragma unroll
    for (int i = 0; i < 4; ++i) {
      int idx = base + (i << 8) + tid;
      if (idx < 65536)       Wx[idx] = f2bf(wxp[idx]);
      else if (idx < 131072) Wz[idx - 65536] = f2bf(wzp[idx - 65536]);
      else if (idx < 196608) Wo[idx - 131072] = f2bf(wop[idx - 131072]);
      else {
        int k = idx - 196608;            // 1280x256 padded
        Wc[k] = ((k >> 8) < 1200) ? f2bf(wcp[k]) : (short)0;
      }
    }
  }

  const float* in = pass ? in1 : in0;
  #pragma unroll 8
  for (int i = 0; i < 32; ++i) {
    int e = (i << 8) + tid;
    int c = e >> 5, lo = e & 31;
    tile[lo * 257 + c] = in[((size_t)(b * 256 + c) << 12) + l0 + lo];
  }
  __syncthreads();
  if (tid < 64) {               // one wave: 32 rows x 2 halves (order-preserving)
    int r = tid & 31, hh = tid >> 5;
    float s = 0.f, ss = 0.f;
    #pragma unroll 16
    for (int c = hh * 128; c < hh * 128 + 128; ++c) {
      float v = tile[r * 257 + c];
      s += v; ss += v * v;
    }
    s  += __shfl_xor(s, 32, 64);
    ss += __shfl_xor(ss, 32, 64);
    if (hh == 0) {
      float m = s * (1.f / 256.f);
      mu[r] = m;
      rs[r] = rsqrtf(ss * (1.f / 256.f) - m * m + 1e-5f);
    }
  }
  __syncthreads();
  const float* w  = pass ? w1 : w0;
  const float* bb = pass ? b1 : b0;
  float wv = w[tid], bv = bb[tid];
  #pragma unroll 8
  for (int i = 0; i < 32; ++i) {
    float v = tile[i * 257 + tid];
    int row = (pass ? 8192 : 0) + (b << 12) + l0 + i;
    xlnz[(size_t)row * 256 + tid] = f2bf((v - mu[i]) * rs[i] * wv + bv);
  }
}

// ---------------------------------------------------------------------------
// K2: fast 128x128 bf16 MFMA GEMM, C[M,N] = A[M,256] * W[N,256]^T
// Double-buffered LDS, single barrier per K-step.
// EPI 0: f32 store N=256; W switches W0->W1 at m>=Msplit (in_proj x|z)
// EPI 2: conv3d: transposed nontemporal f32x4 store + bias[n]
// ---------------------------------------------------------------------------
template <int EPI>
__global__ __launch_bounds__(256) void gemm_fast(
    const short* __restrict__ A, const short* __restrict__ W0,
    const short* __restrict__ W1, float* __restrict__ Cf,
    short* __restrict__ Cb, const float* __restrict__ ADD,
    const float* __restrict__ bias, int Msplit)
{
  __shared__ short As[2][4096];   // [buf][128][32] bf16 (global_load_lds layout)
  __shared__ short Bs[2][4096];
  const int tid  = threadIdx.x;
  const int lane = tid & 63, wave = tid >> 6;
  const int m0 = blockIdx.y << 7;
  const int n0 = blockIdx.x << 7;
  const short* W = (EPI == 0 && m0 >= Msplit) ? W1 : W0;

  const int sr = tid >> 2;
  const int sc = (tid & 3) << 3;
  const int mf = lane & 15, kq = lane >> 4;
  const int wm = (wave & 1) << 6, wn = (wave >> 1) << 6;

  const short* Ar0 = A + (size_t)(m0 + sr) * 256 + sc;
  const short* Ar1 = A + (size_t)(m0 + 64 + sr) * 256 + sc;
  const short* Br0 = W + (size_t)(n0 + sr) * 256 + sc;
  const short* Br1 = W + (size_t)(n0 + 64 + sr) * 256 + sc;
  const int wo = wave << 9;

  f32x4 acc[4][4] = {};

  gl_lds16(Ar0, &As[0][wo]);
  gl_lds16(Ar1, &As[0][wo + 2048]);
  gl_lds16(Br0, &Bs[0][wo]);
  gl_lds16(Br1, &Bs[0][wo + 2048]);
  __syncthreads();

  #pragma unroll
  for (int t = 0; t < 8; ++t) {
    const int cur = t & 1;
    if (t < 7) {                       // issue next-tile stage EARLY
      const int kt = (t + 1) << 5;
      gl_lds16(Ar0 + kt, &As[cur ^ 1][wo]);
      gl_lds16(Ar1 + kt, &As[cur ^ 1][wo + 2048]);
      gl_lds16(Br0 + kt, &Bs[cur ^ 1][wo]);
      gl_lds16(Br1 + kt, &Bs[cur ^ 1][wo + 2048]);
    }
    s16x8 af[4], bfr[4];
    #pragma unroll
    for (int i = 0; i < 4; ++i)
      af[i] = *(const s16x8*)&As[cur][((wm + (i << 4) + mf) << 5) + (kq << 3)];
    #pragma unroll
    for (int j = 0; j < 4; ++j)
      bfr[j] = *(const s16x8*)&Bs[cur][((wn + (j << 4) + mf) << 5) + (kq << 3)];
    #pragma unroll
    for (int i = 0; i < 4; ++i)
      #pragma unroll
      for (int j = 0; j < 4; ++j)
        acc[i][j] = __builtin_amdgcn_mfma_f32_16x16x32_bf16(af[i], bfr[j], acc[i][j], 0, 0, 0);
    __syncthreads();
  }

  if (EPI == 0) {
    #pragma unroll
    for (int i = 0; i < 4; ++i) {
      int gm = m0 + wm + (i << 4) + (kq << 2);
      #pragma unroll
      for (int j = 0; j < 4; ++j) {
        int gn = n0 + wn + (j << 4) + mf;
        #pragma unroll
        for (int r = 0; r < 4; ++r)
          Cf[(size_t)(gm + r) * 256 + gn] = acc[i][j][r];
      }
    }
  } else {
    const int head = m0 >> 13, bb = (m0 >> 12) & 1, lb = m0 & 4095;
    float* obase = Cf + (size_t)head * (2u * 1200u * 4096u) + (size_t)bb * (1200u * 4096u);
    #pragma unroll
    for (int i = 0; i < 4; ++i) {
      int l = lb + wm + (i << 4) + (kq << 2);
      #pragma unroll
      for (int j = 0; j < 4; ++j) {
        int gn = n0 + wn + (j << 4) + mf;
        if (gn < 1200) {
          float bv = bias[gn];
          f32x4 v = acc[i][j];
          v[0] += bv; v[1] += bv; v[2] += bv; v[3] += bv;
          __builtin_nontemporal_store(v, (f32x4*)&obase[(size_t)gn * 4096 + l]);
        }
      }
    }
  }
}

// ---------------------------------------------------------------------------
// K3: fused front per direction: conv1d+SiLU -> xproj -> dtproj -> scan p1.
// grid: 1024 = dir(2) x b(2) x ch(256); 256 threads (d / (s,j))
// ---------------------------------------------------------------------------
__global__ __launch_bounds__(256) void fused_front(
    const float* __restrict__ x,
    const float* __restrict__ cw0, const float* __restrict__ cb0,
    const float* __restrict__ cw1, const float* __restrict__ cb1,
    const float* __restrict__ xw0, const float* __restrict__ xw1,
    const float* __restrict__ dtw0, const float* __restrict__ dtb0,
    const float* __restrict__ dtw1, const float* __restrict__ dtb1,
    const float* __restrict__ Alog0, const float* __restrict__ Alog1,
    float* __restrict__ xcg, float* __restrict__ dblg,
    float* __restrict__ P, float* __restrict__ Q)
{
  __shared__ float xcs[16 * 256];     // 16 KB
  __shared__ short wxs[256 * 33];     // 16.9 KB, transposed [r][33]
  __shared__ float dls[512];          // 2 KB
  const int tid = threadIdx.x;
  const int dir = blockIdx.x >> 9;
  const int b   = (blockIdx.x >> 8) & 1;
  const int ch  = blockIdx.x & 255;
  const int t0  = ch << 4;
  const float* cw   = dir ? cw1 : cw0;
  const float* cb   = dir ? cb1 : cb0;
  const float* xw   = dir ? xw1 : xw0;
  const float* dtw  = dir ? dtw1 : dtw0;
  const float* dtb  = dir ? dtb1 : dtb0;
  const float* Alog = dir ? Alog1 : Alog0;
  const size_t dS = (size_t)dir * (NTOK * 256);
  const size_t xb = ((size_t)b) << 12;

  // --- conv1d + SiLU (depthwise; thread = channel d) ---
  {
    const int d = tid;
    const float w0 = cw[(d << 2)], w1 = cw[(d << 2) + 1],
                w2 = cw[(d << 2) + 2], w3 = cw[(d << 2) + 3];
    const float bias = cb[d];
    float h0 = 0.f, h1 = 0.f, h2 = 0.f;
    #pragma unroll
    for (int i = 0; i < 3; ++i) {
      int ts = t0 - 3 + i; float v = 0.f;
      if (ts >= 0) { int tn = dir ? 4095 - ts : ts; v = x[(xb + tn) * 256 + d]; }
      h0 = h1; h1 = h2; h2 = v;
    }
    #pragma unroll
    for (int s = 0; s < 16; ++s) {
      int ts = t0 + s;
      int tn = dir ? 4095 - ts : ts;
      float xv = x[(xb + tn) * 256 + d];
      float a = bias + w0 * h0 + w1 * h1 + w2 * h2 + w3 * xv;
      h0 = h1; h1 = h2; h2 = xv;
      float v = a / (1.f + __expf(-a));
      xcs[s * 256 + d] = v;
      xcg[dS + (xb + ts) * 256 + d] = v;
    }
  }
  // --- stage xproj weights (bf16, transposed, stride 33) ---
  #pragma unroll
  for (int i = 0; i < 32; ++i) {
    int flat = (i << 8) + tid;          // j = i, r = tid
    wxs[(flat & 255) * 33 + (flat >> 8)] = f2bf(xw[flat]);
  }
  __syncthreads();

  // --- xproj: thread -> (j = tid&31, s0 = tid>>5 and s0+8) ---
  {
    const int j = tid & 31, s0 = tid >> 5;
    float a0 = 0.f, a1 = 0.f;
    #pragma unroll 8
    for (int r = 0; r < 256; ++r) {
      float w = bf2f(wxs[r * 33 + j]);
      a0 = fmaf(xcs[s0 * 256 + r], w, a0);
      a1 = fmaf(xcs[(s0 + 8) * 256 + r], w, a1);
    }
    dls[(s0 << 5) + j] = a0;
    dls[((s0 + 8) << 5) + j] = a1;
    size_t db = (size_t)dir * 262144 + ((xb + t0) << 5);
    dblg[db + tid] = a0;
    dblg[db + 256 + tid] = a1;
  }
  __syncthreads();

  // --- dtproj (softplus) + scan phase-1 (thread = channel d) ---
  {
    const int d = tid;
    float wrow[16];
    #pragma unroll
    for (int r = 0; r < 16; ++r) wrow[r] = dtw[(d << 4) + r];
    const float bias = dtb[d];
    float Av[8], p[8], q[8];
    #pragma unroll
    for (int n = 0; n < 8; ++n) {
      Av[n] = -expf(Alog[(d << 3) + n]); p[n] = 1.f; q[n] = 0.f;
    }
    for (int s = 0; s < 16; ++s) {
      float a = bias;
      #pragma unroll
      for (int r = 0; r < 16; ++r) a = fmaf(dls[(s << 5) + r], wrow[r], a);
      float dtv = (a > 20.f) ? a : log1pf(__expf(a));
      float xv = xcs[s * 256 + d];
      float du = dtv * xv;
      #pragma unroll
      for (int n = 0; n < 8; ++n) {
        float dA = __expf(dtv * Av[n]);
        p[n] *= dA;
        q[n] = fmaf(q[n], dA, du * dls[(s << 5) + 16 + n]);
      }
    }
    size_t ob = (size_t)dir * 1048576 + ((size_t)((b << 8) + ch) * 8) * 256 + d;
    #pragma unroll
    for (int n = 0; n < 8; ++n) { P[ob + (n << 8)] = p[n]; Q[ob + (n << 8)] = q[n]; }
  }
}

// ---------------------------------------------------------------------------
// K4: inter-chunk scan, both dirs. grid 128 = dir(2) x b(2) x n(8) x dq(4),
// 64 threads (d-quarter).
// ---------------------------------------------------------------------------
__global__ __launch_bounds__(64) void scan_p2(
    const float* __restrict__ P, const float* __restrict__ Q, float* __restrict__ Hs)
{
  const int d   = ((blockIdx.x & 3) << 6) + threadIdx.x;
  const int bid = blockIdx.x >> 2;
  const int dir = bid >> 4, b = (bid >> 3) & 1, n = bid & 7;
  const size_t dOff = (size_t)dir * 1048576;
  float h = 0.f;
  #pragma unroll 8
  for (int ch = 0; ch < 256; ++ch) {
    size_t i = dOff + ((size_t)((b << 8) + ch) * 8 + n) * 256 + d;
    Hs[i] = h;
    h = fmaf(P[i], h, Q[i]);
  }
}

// ---------------------------------------------------------------------------
// K5: scan phase-3 (replay + dtproj + D + silu(z) gate), both dirs, bf16 out.
// grid: 1024 = dir(2) x b(2) x ch(256), 256 threads (d)
// ---------------------------------------------------------------------------
__global__ __launch_bounds__(256) void scan_p3(
    const float* __restrict__ xcg, const float* __restrict__ dblg,
    const float* __restrict__ dtw0, const float* __restrict__ dtb0,
    const float* __restrict__ dtw1, const float* __restrict__ dtb1,
    const float* __restrict__ Hs, const float* __restrict__ z,
    const float* __restrict__ Alog0, const float* __restrict__ Alog1,
    const float* __restrict__ Dp0, const float* __restrict__ Dp1,
    short* __restrict__ yall)
{
  __shared__ float dl[512];
  const int d = threadIdx.x;
  const int dir = blockIdx.x >> 9;
  const int b   = (blockIdx.x >> 8) & 1;
  const int ch  = blockIdx.x & 255;
  const int t0  = ch << 4;
  const float* dtw  = dir ? dtw1 : dtw0;
  const float* dtb  = dir ? dtb1 : dtb0;
  const float* Alog = dir ? Alog1 : Alog0;
  const float* Dp   = dir ? Dp1 : Dp0;
  const size_t dS = (size_t)dir * (NTOK * 256);
  const size_t xb = ((size_t)b) << 12;
  short* y = yall + (size_t)dir * (NTOK * 256);

  size_t db = (size_t)dir * 262144 + ((xb + t0) << 5);
  dl[d]       = dblg[db + d];
  dl[256 + d] = dblg[db + 256 + d];
  float wrow[16];
  #pragma unroll
  for (int r = 0; r < 16; ++r) wrow[r] = dtw[(d << 4) + r];
  const float bias = dtb[d];
  float Av[8], h[8];
  #pragma unroll
  for (int n = 0; n < 8; ++n) Av[n] = -expf(Alog[(d << 3) + n]);
  size_t hb = (size_t)dir * 1048576 + ((size_t)((b << 8) + ch) * 8) * 256 + d;
  #pragma unroll
  for (int n = 0; n < 8; ++n) h[n] = Hs[hb + (n << 8)];
  const float Dv = Dp[d];
  __syncthreads();
  for (int s = 0; s < 16; ++s) {
    float a = bias;
    #pragma unroll
    for (int r = 0; r < 16; ++r) a = fmaf(dl[(s << 5) + r], wrow[r], a);
    float dtv = (a > 20.f) ? a : log1pf(__expf(a));
    int ts = t0 + s;
    float xv = xcg[dS + (xb + ts) * 256 + d];
    float du = dtv * xv;
    float yv = 0.f;
    #pragma unroll
    for (int n = 0; n < 8; ++n) {
      float dA = __expf(dtv * Av[n]);
      h[n] = fmaf(h[n], dA, du * dl[(s << 5) + 16 + n]);
      yv = fmaf(h[n], dl[(s << 5) + 24 + n], yv);
    }
    yv = fmaf(xv, Dv, yv);
    int tn = dir ? (4095 - ts) : ts;
    size_t zi = (xb + tn) * 256 + d;
    float zv = z[zi];
    y[zi] = f2bf(yv * zv / (1.f + __expf(-zv)));
  }
}

// ---------------------------------------------------------------------------
// K6: EPI1 GEMM with fused RMSNorm of A-rows (replaces rms_all + gemm<1>).
// mode = m0>>13: 0=avg(yf,yb), 1=yf, 2=yb. Pass 1 reproduces rms_all's
// exact reduction order; pass 2 reg-stages rms-scaled bf16 A-chunks to LDS.
// Skip-add reads in0 DIRECTLY (transposed f32x4; seqT eliminated).
// C = bf16(A_rms * Wo^T + skip) -> obuf.  grid (2,192), 256 thr.
// ---------------------------------------------------------------------------
__global__ __launch_bounds__(256) void gemm_rms_epi1(
    const short* __restrict__ yall, const short* __restrict__ W0,
    const float* __restrict__ rmsw, short* __restrict__ Cb,
    const float* __restrict__ in0)
{
  __shared__ short As[4096];          // [128][32]
  __shared__ short Bs[4096];
  __shared__ float scale[128];
  __shared__ float rw[256];
  const int tid  = threadIdx.x;
  const int lane = tid & 63, wave = tid >> 6;
  const int m0 = blockIdx.y << 7;
  const int n0 = blockIdx.x << 7;
  const int mode = m0 >> 13;
  const int tok0 = m0 & 8191;
  const short* yf = yall;
  const short* yb = yall + 2097152;
  const short* ysel = (mode == 1) ? yf : yb;

  rw[tid] = rmsw[tid];

  // pass 1: per-row sumsq, identical order to old rms_all (wave per row)
  for (int rr = 0; rr < 32; ++rr) {
    int r = (rr << 2) + wave;
    size_t base = (size_t)(tok0 + r) * 256 + (lane << 2);
    float v0, v1, v2, v3;
    if (mode == 0) {
      s16x4 a = *(const s16x4*)&yf[base];
      s16x4 c = *(const s16x4*)&yb[base];
      v0 = 0.5f * (bf2f(a[0]) + bf2f(c[0]));
      v1 = 0.5f * (bf2f(a[1]) + bf2f(c[1]));
      v2 = 0.5f * (bf2f(a[2]) + bf2f(c[2]));
      v3 = 0.5f * (bf2f(a[3]) + bf2f(c[3]));
    } else {
      s16x4 a = *(const s16x4*)&ysel[base];
      v0 = bf2f(a[0]); v1 = bf2f(a[1]); v2 = bf2f(a[2]); v3 = bf2f(a[3]);
    }
    float ss = v0 * v0 + v1 * v1 + v2 * v2 + v3 * v3;
    #pragma unroll
    for (int o = 32; o > 0; o >>= 1) ss += __shfl_xor(ss, o, 64);
    if (lane == 0) scale[r] = rsqrtf(ss * (1.f / 256.f) + 1e-5f);
  }
  __syncthreads();

  const int sr = tid >> 2;
  const int sc = (tid & 3) << 3;
  const int mf = lane & 15, kq = lane >> 4;
  const int wm = (wave & 1) << 6, wn = (wave >> 1) << 6;
  const short* Br0 = W0 + (size_t)(n0 + sr) * 256 + sc;
  const short* Br1 = W0 + (size_t)(n0 + 64 + sr) * 256 + sc;
  const int wo = wave << 9;

  const int ar = tid >> 1;            // A-stage: 2 threads per row
  const int ac = (tid & 1) << 4;      // 16 cols each
  const size_t abase = (size_t)(tok0 + ar) * 256 + ac;
  const float s_r = scale[ar];

  f32x4 acc[4][4] = {};

  for (int t = 0; t < 8; ++t) {
    const int kt = t << 5;
    // stage A chunk: load (L2-hot), rms-scale, round to bf16, ds_write
    {
      s16x8 o0, o1;
      if (mode == 0) {
        s16x8 f0 = *(const s16x8*)&yf[abase + kt];
        s16x8 f1 = *(const s16x8*)&yf[abase + kt + 8];
        s16x8 c0 = *(const s16x8*)&yb[abase + kt];
        s16x8 c1 = *(const s16x8*)&yb[abase + kt + 8];
        #pragma unroll
        for (int e = 0; e < 8; ++e) {
          o0[e] = f2bf((0.5f * (bf2f(f0[e]) + bf2f(c0[e])) * s_r) * rw[kt + ac + e]);
          o1[e] = f2bf((0.5f * (bf2f(f1[e]) + bf2f(c1[e])) * s_r) * rw[kt + ac + 8 + e]);
        }
      } else {
        s16x8 f0 = *(const s16x8*)&ysel[abase + kt];
        s16x8 f1 = *(const s16x8*)&ysel[abase + kt + 8];
        #pragma unroll
        for (int e = 0; e < 8; ++e) {
          o0[e] = f2bf((bf2f(f0[e]) * s_r) * rw[kt + ac + e]);
          o1[e] = f2bf((bf2f(f1[e]) * s_r) * rw[kt + ac + 8 + e]);
        }
      }
      *(s16x8*)&As[(ar << 5) + ac]     = o0;
      *(s16x8*)&As[(ar << 5) + ac + 8] = o1;
    }
    gl_lds16(Br0 + kt, &Bs[wo]);
    gl_lds16(Br1 + kt, &Bs[wo + 2048]);
    __syncthreads();
    s16x8 af[4], bfr[4];
    #pragma unroll
    for (int i = 0; i < 4; ++i)
      af[i] = *(const s16x8*)&As[((wm + (i << 4) + mf) << 5) + (kq << 3)];
    #pragma unroll
    for (int j = 0; j < 4; ++j)
      bfr[j] = *(const s16x8*)&Bs[((wn + (j << 4) + mf) << 5) + (kq << 3)];
    #pragma unroll
    for (int i = 0; i < 4; ++i)
      #pragma unroll
      for (int j = 0; j < 4; ++j)
        acc[i][j] = __builtin_amdgcn_mfma_f32_16x16x32_bf16(af[i], bfr[j], acc[i][j], 0, 0, 0);
    __syncthreads();
  }

  #pragma unroll
  for (int i = 0; i < 4; ++i) {
    int gm = m0 + wm + (i << 4) + (kq << 2);
    int tok = gm & 8191;                 // 4-aligned; never crosses 4096
    int bb2 = tok >> 12, ll = tok & 4095;
    #pragma unroll
    for (int j = 0; j < 4; ++j) {
      int gn = n0 + wn + (j << 4) + mf;
      // skip = in0[b][gn][l..l+3] (contiguous f32x4)
      f32x4 sk = *(const f32x4*)&in0[((((size_t)(bb2 << 8)) + gn) << 12) + ll];
      #pragma unroll
      for (int r = 0; r < 4; ++r) {
        float v = acc[i][j][r] + sk[r];
        Cb[(size_t)(gm + r) * 256 + gn] = f2bf(v);
      }
    }
  }
}

// ---------------------------------------------------------------------------
extern "C" void kernel_launch(void* const* d_in, const int* in_sizes, int n_in,
                              void* d_out, int out_size, void* d_ws, size_t ws_size,
                              hipStream_t stream) {
  const float* in0        = (const float*)d_in[0];
  const float* in1        = (const float*)d_in[1];
  const float* n0w        = (const float*)d_in[2];
  const float* n0b        = (const float*)d_in[3];
  const float* n1w        = (const float*)d_in[4];
  const float* n1b        = (const float*)d_in[5];
  const float* in_proj_w  = (const float*)d_in[6];
  const float* in_projz_w = (const float*)d_in[7];
  const float* conv1d_w   = (const float*)d_in[8];
  const float* conv1d_b   = (const float*)d_in[9];
  const float* conv1db_w  = (const float*)d_in[10];
  const float* conv1db_b  = (const float*)d_in[11];
  const float* xproj_w    = (const float*)d_in[12];
  const float* xprojb_w   = (const float*)d_in[13];
  const float* dtproj_w   = (const float*)d_in[14];
  const float* dtproj_b   = (const float*)d_in[15];
  const float* dtprojb_w  = (const float*)d_in[16];
  const float* dtprojb_b  = (const float*)d_in[17];
  const float* A_log      = (const float*)d_in[18];
  const float* Ab_log     = (const float*)d_in[19];
  const float* D_p        = (const float*)d_in[20];
  const float* D_b        = (const float*)d_in[21];
  const float* rms_w      = (const float*)d_in[22];
  const float* out_proj_w = (const float*)d_in[23];
  const float* conv3d_w   = (const float*)d_in[24];
  const float* conv3d_b   = (const float*)d_in[25];
  (void)in_sizes; (void)n_in; (void)out_size; (void)ws_size;

  float* ws = (float*)d_ws;
  size_t o = 0;
  short* xlnz = (short*)(ws + o); o += 2097152;   // 16384x256 bf16
  float* x    = ws + o;           o += 2097152;   // x then z contiguous
  float* z    = ws + o;           o += 2097152;
  float* xc2  = ws + o;           o += 4194304;   // 2 dirs x 8192x256 f32
  float* dbl2 = ws + o;           o += 524288;    // 2 dirs x 8192x32
  float* P    = ws + o;           o += 2097152;   // 2 dirs x 1M
  float* Q    = ws + o;           o += 2097152;
  float* Hs   = ws + o;           o += 2097152;
  short* yall = (short*)(ws + o); o += 2097152;   // 2 dirs x 8192x256 bf16
  short* obuf = (short*)(ws + o); o += 3145728;
  short* Wx   = (short*)(ws + o); o += 32768;
  short* Wz   = (short*)(ws + o); o += 32768;
  short* Wo   = (short*)(ws + o); o += 32768;
  short* Wc   = (short*)(ws + o); o += 163840;    // 1280x256 bf16 padded
  float* out  = (float*)d_out;

  dim3 blk(256);

  ln_transpose_kernel<<<dim3(512), blk, 0, stream>>>(
      in0, in1, n0w, n0b, n1w, n1b,
      in_proj_w, in_projz_w, out_proj_w, conv3d_w, Wx, Wz, Wo, Wc,
      xlnz);

  // in_proj: x|z batched (M=16384, weight switch at 8192)
  gemm_fast<0><<<dim3(2, 128), blk, 0, stream>>>(xlnz, Wx, Wz, x, nullptr, nullptr, nullptr, 8192);

  // both directions: conv+silu -> xproj -> dtproj -> scan p1
  fused_front<<<dim3(1024), blk, 0, stream>>>(
      x, conv1d_w, conv1d_b, conv1db_w, conv1db_b,
      xproj_w, xprojb_w, dtproj_w, dtproj_b, dtprojb_w, dtprojb_b,
      A_log, Ab_log, xc2, dbl2, P, Q);

  scan_p2<<<dim3(128), dim3(64), 0, stream>>>(P, Q, Hs);

  scan_p3<<<dim3(1024), blk, 0, stream>>>(
      xc2, dbl2, dtproj_w, dtproj_b, dtprojb_w, dtprojb_b,
      Hs, z, A_log, Ab_log, D_p, D_b, yall);

  // heads: rms fused into out_proj+skip (batched) -> conv3d (batched)
  gemm_rms_epi1<<<dim3(2, 192), blk, 0, stream>>>(yall, Wo, rms_w, obuf, in0);
  gemm_fast<2><<<dim3(10, 192), blk, 0, stream>>>(obuf, Wc, nullptr, out, nullptr, nullptr, conv3d_b, 0);
}

// Round 8
// 333.103 us; speedup vs baseline: 1.5142x; 1.0374x over previous
//
#include <hip/hip_runtime.h>
#include <cstdint>

#define NTOK 8192

typedef __attribute__((ext_vector_type(4))) float f32x4;
typedef __attribute__((ext_vector_type(8))) short s16x8;
typedef __attribute__((ext_vector_type(4))) short s16x4;

__device__ __forceinline__ short f2bf(float f) {
  union { float f; unsigned u; } x; x.f = f;
  unsigned r = x.u + 0x7FFFu + ((x.u >> 16) & 1u);
  return (short)(r >> 16);
}
__device__ __forceinline__ float bf2f(short s) {
  union { float f; unsigned u; } x;
  x.u = ((unsigned)(unsigned short)s) << 16;
  return x.f;
}
__device__ __forceinline__ void gl_lds16(const void* g, void* l) {
  __builtin_amdgcn_global_load_lds((const unsigned int*)g, (unsigned int*)l, 16, 0, 0);
}

// ---------------------------------------------------------------------------
// K1: transpose (B,DIM,L)->(B,L,DIM) + LayerNorm both inputs (bf16 out);
// converts the 4 big weight matrices to bf16.
// grid: 512 blocks, 256 threads
// ---------------------------------------------------------------------------
__global__ __launch_bounds__(256) void ln_transpose_kernel(
    const float* __restrict__ in0, const float* __restrict__ in1,
    const float* __restrict__ w0, const float* __restrict__ b0,
    const float* __restrict__ w1, const float* __restrict__ b1,
    const float* __restrict__ wxp, const float* __restrict__ wzp,
    const float* __restrict__ wop, const float* __restrict__ wcp,
    short* __restrict__ Wx, short* __restrict__ Wz,
    short* __restrict__ Wo, short* __restrict__ Wc,
    short* __restrict__ xlnz)
{
  __shared__ float tile[32 * 257];
  __shared__ float mu[32], rs[32];
  const int tid  = threadIdx.x;
  const int pass = blockIdx.x >> 8;
  const int b    = (blockIdx.x >> 7) & 1;
  const int l0   = (blockIdx.x & 127) << 5;

  // weight conversion: 1024 elements per block (512*1024 = 524288 total)
  {
    int base = (int)blockIdx.x << 10;
    #pragma unroll
    for (int i = 0; i < 4; ++i) {
      int idx = base + (i << 8) + tid;
      if (idx < 65536)       Wx[idx] = f2bf(wxp[idx]);
      else if (idx < 131072) Wz[idx - 65536] = f2bf(wzp[idx - 65536]);
      else if (idx < 196608) Wo[idx - 131072] = f2bf(wop[idx - 131072]);
      else {
        int k = idx - 196608;            // 1280x256 padded
        Wc[k] = ((k >> 8) < 1200) ? f2bf(wcp[k]) : (short)0;
      }
    }
  }

  const float* in = pass ? in1 : in0;
  #pragma unroll 8
  for (int i = 0; i < 32; ++i) {
    int e = (i << 8) + tid;
    int c = e >> 5, lo = e & 31;
    tile[lo * 257 + c] = in[((size_t)(b * 256 + c) << 12) + l0 + lo];
  }
  __syncthreads();
  if (tid < 64) {               // one wave: 32 rows x 2 halves (order-preserving)
    int r = tid & 31, hh = tid >> 5;
    float s = 0.f, ss = 0.f;
    #pragma unroll 16
    for (int c = hh * 128; c < hh * 128 + 128; ++c) {
      float v = tile[r * 257 + c];
      s += v; ss += v * v;
    }
    s  += __shfl_xor(s, 32, 64);
    ss += __shfl_xor(ss, 32, 64);
    if (hh == 0) {
      float m = s * (1.f / 256.f);
      mu[r] = m;
      rs[r] = rsqrtf(ss * (1.f / 256.f) - m * m + 1e-5f);
    }
  }
  __syncthreads();
  const float* w  = pass ? w1 : w0;
  const float* bb = pass ? b1 : b0;
  float wv = w[tid], bv = bb[tid];
  #pragma unroll 8
  for (int i = 0; i < 32; ++i) {
    float v = tile[i * 257 + tid];
    int row = (pass ? 8192 : 0) + (b << 12) + l0 + i;
    xlnz[(size_t)row * 256 + tid] = f2bf((v - mu[i]) * rs[i] * wv + bv);
  }
}

// ---------------------------------------------------------------------------
// K2: fast 128x128 bf16 MFMA GEMM, C[M,N] = A[M,256] * W[N,256]^T
// Double-buffered LDS, single barrier per K-step.
// EPI 0: f32 store N=256; W switches W0->W1 at m>=Msplit (in_proj x|z)
// EPI 2: conv3d: transposed nontemporal f32x4 store + bias[n]
// ---------------------------------------------------------------------------
template <int EPI>
__global__ __launch_bounds__(256) void gemm_fast(
    const short* __restrict__ A, const short* __restrict__ W0,
    const short* __restrict__ W1, float* __restrict__ Cf,
    short* __restrict__ Cb, const float* __restrict__ ADD,
    const float* __restrict__ bias, int Msplit)
{
  __shared__ short As[2][4096];   // [buf][128][32] bf16 (global_load_lds layout)
  __shared__ short Bs[2][4096];
  const int tid  = threadIdx.x;
  const int lane = tid & 63, wave = tid >> 6;
  const int m0 = blockIdx.y << 7;
  const int n0 = blockIdx.x << 7;
  const short* W = (EPI == 0 && m0 >= Msplit) ? W1 : W0;

  const int sr = tid >> 2;
  const int sc = (tid & 3) << 3;
  const int mf = lane & 15, kq = lane >> 4;
  const int wm = (wave & 1) << 6, wn = (wave >> 1) << 6;

  const short* Ar0 = A + (size_t)(m0 + sr) * 256 + sc;
  const short* Ar1 = A + (size_t)(m0 + 64 + sr) * 256 + sc;
  const short* Br0 = W + (size_t)(n0 + sr) * 256 + sc;
  const short* Br1 = W + (size_t)(n0 + 64 + sr) * 256 + sc;
  const int wo = wave << 9;

  f32x4 acc[4][4] = {};

  gl_lds16(Ar0, &As[0][wo]);
  gl_lds16(Ar1, &As[0][wo + 2048]);
  gl_lds16(Br0, &Bs[0][wo]);
  gl_lds16(Br1, &Bs[0][wo + 2048]);
  __syncthreads();

  #pragma unroll
  for (int t = 0; t < 8; ++t) {
    const int cur = t & 1;
    if (t < 7) {                       // issue next-tile stage EARLY
      const int kt = (t + 1) << 5;
      gl_lds16(Ar0 + kt, &As[cur ^ 1][wo]);
      gl_lds16(Ar1 + kt, &As[cur ^ 1][wo + 2048]);
      gl_lds16(Br0 + kt, &Bs[cur ^ 1][wo]);
      gl_lds16(Br1 + kt, &Bs[cur ^ 1][wo + 2048]);
    }
    s16x8 af[4], bfr[4];
    #pragma unroll
    for (int i = 0; i < 4; ++i)
      af[i] = *(const s16x8*)&As[cur][((wm + (i << 4) + mf) << 5) + (kq << 3)];
    #pragma unroll
    for (int j = 0; j < 4; ++j)
      bfr[j] = *(const s16x8*)&Bs[cur][((wn + (j << 4) + mf) << 5) + (kq << 3)];
    #pragma unroll
    for (int i = 0; i < 4; ++i)
      #pragma unroll
      for (int j = 0; j < 4; ++j)
        acc[i][j] = __builtin_amdgcn_mfma_f32_16x16x32_bf16(af[i], bfr[j], acc[i][j], 0, 0, 0);
    __syncthreads();
  }

  if (EPI == 0) {
    #pragma unroll
    for (int i = 0; i < 4; ++i) {
      int gm = m0 + wm + (i << 4) + (kq << 2);
      #pragma unroll
      for (int j = 0; j < 4; ++j) {
        int gn = n0 + wn + (j << 4) + mf;
        #pragma unroll
        for (int r = 0; r < 4; ++r)
          Cf[(size_t)(gm + r) * 256 + gn] = acc[i][j][r];
      }
    }
  } else {
    const int head = m0 >> 13, bb = (m0 >> 12) & 1, lb = m0 & 4095;
    float* obase = Cf + (size_t)head * (2u * 1200u * 4096u) + (size_t)bb * (1200u * 4096u);
    #pragma unroll
    for (int i = 0; i < 4; ++i) {
      int l = lb + wm + (i << 4) + (kq << 2);
      #pragma unroll
      for (int j = 0; j < 4; ++j) {
        int gn = n0 + wn + (j << 4) + mf;
        if (gn < 1200) {
          float bv = bias[gn];
          f32x4 v = acc[i][j];
          v[0] += bv; v[1] += bv; v[2] += bv; v[3] += bv;
          __builtin_nontemporal_store(v, (f32x4*)&obase[(size_t)gn * 4096 + l]);
        }
      }
    }
  }
}

// ---------------------------------------------------------------------------
// K3: fused front per direction: conv1d+SiLU -> xproj -> dtproj -> scan p1.
// xproj LDS-vectorized: weights stored [j][r] stride 264, read s16x8;
// xcs read f32x4 (5 LDS ops per 16 FMA vs 24). Same FMA order (r ascending).
// grid: 1024 = dir(2) x b(2) x ch(256); 256 threads (d / (s,j))
// ---------------------------------------------------------------------------
__global__ __launch_bounds__(256) void fused_front(
    const float* __restrict__ x,
    const float* __restrict__ cw0, const float* __restrict__ cb0,
    const float* __restrict__ cw1, const float* __restrict__ cb1,
    const float* __restrict__ xw0, const float* __restrict__ xw1,
    const float* __restrict__ dtw0, const float* __restrict__ dtb0,
    const float* __restrict__ dtw1, const float* __restrict__ dtb1,
    const float* __restrict__ Alog0, const float* __restrict__ Alog1,
    float* __restrict__ xcg, float* __restrict__ dblg,
    float* __restrict__ P, float* __restrict__ Q)
{
  __shared__ float xcs[16 * 256];     // 16 KB
  __shared__ short wxs[32 * 264];     // 16.5 KB, [j][r] stride 264
  __shared__ float dls[512];          // 2 KB
  const int tid = threadIdx.x;
  const int dir = blockIdx.x >> 9;
  const int b   = (blockIdx.x >> 8) & 1;
  const int ch  = blockIdx.x & 255;
  const int t0  = ch << 4;
  const float* cw   = dir ? cw1 : cw0;
  const float* cb   = dir ? cb1 : cb0;
  const float* xw   = dir ? xw1 : xw0;
  const float* dtw  = dir ? dtw1 : dtw0;
  const float* dtb  = dir ? dtb1 : dtb0;
  const float* Alog = dir ? Alog1 : Alog0;
  const size_t dS = (size_t)dir * (NTOK * 256);
  const size_t xb = ((size_t)b) << 12;

  // --- conv1d + SiLU (depthwise; thread = channel d) ---
  {
    const int d = tid;
    const float w0 = cw[(d << 2)], w1 = cw[(d << 2) + 1],
                w2 = cw[(d << 2) + 2], w3 = cw[(d << 2) + 3];
    const float bias = cb[d];
    float h0 = 0.f, h1 = 0.f, h2 = 0.f;
    #pragma unroll
    for (int i = 0; i < 3; ++i) {
      int ts = t0 - 3 + i; float v = 0.f;
      if (ts >= 0) { int tn = dir ? 4095 - ts : ts; v = x[(xb + tn) * 256 + d]; }
      h0 = h1; h1 = h2; h2 = v;
    }
    #pragma unroll
    for (int s = 0; s < 16; ++s) {
      int ts = t0 + s;
      int tn = dir ? 4095 - ts : ts;
      float xv = x[(xb + tn) * 256 + d];
      float a = bias + w0 * h0 + w1 * h1 + w2 * h2 + w3 * xv;
      h0 = h1; h1 = h2; h2 = xv;
      float v = a / (1.f + __expf(-a));
      xcs[s * 256 + d] = v;
      xcg[dS + (xb + ts) * 256 + d] = v;
    }
  }
  // --- stage xproj weights (bf16, [j][r] row-major, stride 264) ---
  #pragma unroll
  for (int i = 0; i < 32; ++i)
    wxs[i * 264 + tid] = f2bf(xw[(i << 8) + tid]);
  __syncthreads();

  // --- xproj: thread -> (j = tid&31, s0 = tid>>5 and s0+8) ---
  {
    const int j = tid & 31, s0 = tid >> 5;
    float a0 = 0.f, a1 = 0.f;
    const short* wr = &wxs[j * 264];
    const float* xa = &xcs[s0 * 256];
    const float* xbp = &xcs[(s0 + 8) * 256];
    #pragma unroll 4
    for (int rb = 0; rb < 32; ++rb) {
      s16x8 w8 = *(const s16x8*)&wr[rb << 3];
      f32x4 p0 = *(const f32x4*)&xa[rb << 3];
      f32x4 p1 = *(const f32x4*)&xa[(rb << 3) + 4];
      f32x4 q0 = *(const f32x4*)&xbp[rb << 3];
      f32x4 q1 = *(const f32x4*)&xbp[(rb << 3) + 4];
      #pragma unroll
      for (int e = 0; e < 4; ++e) {
        float w = bf2f(w8[e]);
        a0 = fmaf(p0[e], w, a0);
        a1 = fmaf(q0[e], w, a1);
      }
      #pragma unroll
      for (int e = 0; e < 4; ++e) {
        float w = bf2f(w8[4 + e]);
        a0 = fmaf(p1[e], w, a0);
        a1 = fmaf(q1[e], w, a1);
      }
    }
    dls[(s0 << 5) + j] = a0;
    dls[((s0 + 8) << 5) + j] = a1;
    size_t db = (size_t)dir * 262144 + ((xb + t0) << 5);
    dblg[db + tid] = a0;
    dblg[db + 256 + tid] = a1;
  }
  __syncthreads();

  // --- dtproj (softplus) + scan phase-1 (thread = channel d) ---
  {
    const int d = tid;
    float wrow[16];
    #pragma unroll
    for (int r = 0; r < 16; ++r) wrow[r] = dtw[(d << 4) + r];
    const float bias = dtb[d];
    float Av[8], p[8], q[8];
    #pragma unroll
    for (int n = 0; n < 8; ++n) {
      Av[n] = -expf(Alog[(d << 3) + n]); p[n] = 1.f; q[n] = 0.f;
    }
    for (int s = 0; s < 16; ++s) {
      const float* dlp = &dls[s << 5];
      f32x4 d0 = *(const f32x4*)&dlp[0];
      f32x4 d1 = *(const f32x4*)&dlp[4];
      f32x4 d2 = *(const f32x4*)&dlp[8];
      f32x4 d3 = *(const f32x4*)&dlp[12];
      float a = bias;
      #pragma unroll
      for (int e = 0; e < 4; ++e) a = fmaf(d0[e], wrow[e], a);
      #pragma unroll
      for (int e = 0; e < 4; ++e) a = fmaf(d1[e], wrow[4 + e], a);
      #pragma unroll
      for (int e = 0; e < 4; ++e) a = fmaf(d2[e], wrow[8 + e], a);
      #pragma unroll
      for (int e = 0; e < 4; ++e) a = fmaf(d3[e], wrow[12 + e], a);
      float dtv = (a > 20.f) ? a : log1pf(__expf(a));
      float xv = xcs[s * 256 + d];
      float du = dtv * xv;
      float Bv[8];
      *(f32x4*)&Bv[0] = *(const f32x4*)&dlp[16];
      *(f32x4*)&Bv[4] = *(const f32x4*)&dlp[20];
      #pragma unroll
      for (int n = 0; n < 8; ++n) {
        float dA = __expf(dtv * Av[n]);
        p[n] *= dA;
        q[n] = fmaf(q[n], dA, du * Bv[n]);
      }
    }
    size_t ob = (size_t)dir * 1048576 + ((size_t)((b << 8) + ch) * 8) * 256 + d;
    #pragma unroll
    for (int n = 0; n < 8; ++n) { P[ob + (n << 8)] = p[n]; Q[ob + (n << 8)] = q[n]; }
  }
}

// ---------------------------------------------------------------------------
// K4: inter-chunk scan, both dirs. grid 128 = dir(2) x b(2) x n(8) x dq(4),
// 64 threads (d-quarter).
// ---------------------------------------------------------------------------
__global__ __launch_bounds__(64) void scan_p2(
    const float* __restrict__ P, const float* __restrict__ Q, float* __restrict__ Hs)
{
  const int d   = ((blockIdx.x & 3) << 6) + threadIdx.x;
  const int bid = blockIdx.x >> 2;
  const int dir = bid >> 4, b = (bid >> 3) & 1, n = bid & 7;
  const size_t dOff = (size_t)dir * 1048576;
  float h = 0.f;
  #pragma unroll 8
  for (int ch = 0; ch < 256; ++ch) {
    size_t i = dOff + ((size_t)((b << 8) + ch) * 8 + n) * 256 + d;
    Hs[i] = h;
    h = fmaf(P[i], h, Q[i]);
  }
}

// ---------------------------------------------------------------------------
// K5: scan phase-3 (replay + dtproj + D + silu(z) gate), both dirs, bf16 out.
// dl reads LDS-vectorized (f32x4 broadcast; 8 ops/step vs 32).
// grid: 1024 = dir(2) x b(2) x ch(256), 256 threads (d)
// ---------------------------------------------------------------------------
__global__ __launch_bounds__(256) void scan_p3(
    const float* __restrict__ xcg, const float* __restrict__ dblg,
    const float* __restrict__ dtw0, const float* __restrict__ dtb0,
    const float* __restrict__ dtw1, const float* __restrict__ dtb1,
    const float* __restrict__ Hs, const float* __restrict__ z,
    const float* __restrict__ Alog0, const float* __restrict__ Alog1,
    const float* __restrict__ Dp0, const float* __restrict__ Dp1,
    short* __restrict__ yall)
{
  __shared__ float dl[512];
  const int d = threadIdx.x;
  const int dir = blockIdx.x >> 9;
  const int b   = (blockIdx.x >> 8) & 1;
  const int ch  = blockIdx.x & 255;
  const int t0  = ch << 4;
  const float* dtw  = dir ? dtw1 : dtw0;
  const float* dtb  = dir ? dtb1 : dtb0;
  const float* Alog = dir ? Alog1 : Alog0;
  const float* Dp   = dir ? Dp1 : Dp0;
  const size_t dS = (size_t)dir * (NTOK * 256);
  const size_t xb = ((size_t)b) << 12;
  short* y = yall + (size_t)dir * (NTOK * 256);

  size_t db = (size_t)dir * 262144 + ((xb + t0) << 5);
  dl[d]       = dblg[db + d];
  dl[256 + d] = dblg[db + 256 + d];
  float wrow[16];
  #pragma unroll
  for (int r = 0; r < 16; ++r) wrow[r] = dtw[(d << 4) + r];
  const float bias = dtb[d];
  float Av[8], h[8];
  #pragma unroll
  for (int n = 0; n < 8; ++n) Av[n] = -expf(Alog[(d << 3) + n]);
  size_t hb = (size_t)dir * 1048576 + ((size_t)((b << 8) + ch) * 8) * 256 + d;
  #pragma unroll
  for (int n = 0; n < 8; ++n) h[n] = Hs[hb + (n << 8)];
  const float Dv = Dp[d];
  __syncthreads();
  for (int s = 0; s < 16; ++s) {
    const float* dlp = &dl[s << 5];
    f32x4 d0 = *(const f32x4*)&dlp[0];
    f32x4 d1 = *(const f32x4*)&dlp[4];
    f32x4 d2 = *(const f32x4*)&dlp[8];
    f32x4 d3 = *(const f32x4*)&dlp[12];
    float a = bias;
    #pragma unroll
    for (int e = 0; e < 4; ++e) a = fmaf(d0[e], wrow[e], a);
    #pragma unroll
    for (int e = 0; e < 4; ++e) a = fmaf(d1[e], wrow[4 + e], a);
    #pragma unroll
    for (int e = 0; e < 4; ++e) a = fmaf(d2[e], wrow[8 + e], a);
    #pragma unroll
    for (int e = 0; e < 4; ++e) a = fmaf(d3[e], wrow[12 + e], a);
    float dtv = (a > 20.f) ? a : log1pf(__expf(a));
    int ts = t0 + s;
    float xv = xcg[dS + (xb + ts) * 256 + d];
    float du = dtv * xv;
    float Bv[8], Cv[8];
    *(f32x4*)&Bv[0] = *(const f32x4*)&dlp[16];
    *(f32x4*)&Bv[4] = *(const f32x4*)&dlp[20];
    *(f32x4*)&Cv[0] = *(const f32x4*)&dlp[24];
    *(f32x4*)&Cv[4] = *(const f32x4*)&dlp[28];
    float yv = 0.f;
    #pragma unroll
    for (int n = 0; n < 8; ++n) {
      float dA = __expf(dtv * Av[n]);
      h[n] = fmaf(h[n], dA, du * Bv[n]);
      yv = fmaf(h[n], Cv[n], yv);
    }
    yv = fmaf(xv, Dv, yv);
    int tn = dir ? (4095 - ts) : ts;
    size_t zi = (xb + tn) * 256 + d;
    float zv = z[zi];
    y[zi] = f2bf(yv * zv / (1.f + __expf(-zv)));
  }
}

// ---------------------------------------------------------------------------
// K6: EPI1 GEMM with fused RMSNorm of A-rows. 64x128 tiles, grid (2,384)
// = 768 blocks (was 384) -> 3 blocks/CU, halves the tail.
// mode = m0>>13: 0=avg(yf,yb), 1=yf, 2=yb. Per-row reduction order and
// per-element math identical to previous version (bit-identical output).
// C = bf16(A_rms * Wo^T + in0 skip) -> obuf.  256 thr.
// ---------------------------------------------------------------------------
__global__ __launch_bounds__(256) void gemm_rms_epi1(
    const short* __restrict__ yall, const short* __restrict__ W0,
    const float* __restrict__ rmsw, short* __restrict__ Cb,
    const float* __restrict__ in0)
{
  __shared__ short As[2048];          // [64][32]
  __shared__ short Bs[4096];          // [128][32]
  __shared__ float scale[64];
  __shared__ float rw[256];
  const int tid  = threadIdx.x;
  const int lane = tid & 63, wave = tid >> 6;
  const int m0 = blockIdx.y << 6;
  const int n0 = blockIdx.x << 7;
  const int mode = m0 >> 13;
  const int tok0 = m0 & 8191;
  const short* yf = yall;
  const short* yb = yall + 2097152;
  const short* ysel = (mode == 1) ? yf : yb;

  rw[tid] = rmsw[tid];

  // pass 1: per-row sumsq (wave per row; same order as before)
  for (int rr = 0; rr < 16; ++rr) {
    int r = (rr << 2) + wave;
    size_t base = (size_t)(tok0 + r) * 256 + (lane << 2);
    float v0, v1, v2, v3;
    if (mode == 0) {
      s16x4 a = *(const s16x4*)&yf[base];
      s16x4 c = *(const s16x4*)&yb[base];
      v0 = 0.5f * (bf2f(a[0]) + bf2f(c[0]));
      v1 = 0.5f * (bf2f(a[1]) + bf2f(c[1]));
      v2 = 0.5f * (bf2f(a[2]) + bf2f(c[2]));
      v3 = 0.5f * (bf2f(a[3]) + bf2f(c[3]));
    } else {
      s16x4 a = *(const s16x4*)&ysel[base];
      v0 = bf2f(a[0]); v1 = bf2f(a[1]); v2 = bf2f(a[2]); v3 = bf2f(a[3]);
    }
    float ss = v0 * v0 + v1 * v1 + v2 * v2 + v3 * v3;
    #pragma unroll
    for (int o = 32; o > 0; o >>= 1) ss += __shfl_xor(ss, o, 64);
    if (lane == 0) scale[r] = rsqrtf(ss * (1.f / 256.f) + 1e-5f);
  }
  __syncthreads();

  const int sr = tid >> 2;
  const int sc = (tid & 3) << 3;
  const int mf = lane & 15, kq = lane >> 4;
  const int wn = wave << 5;           // 4 waves x 32 N-cols
  const short* Br0 = W0 + (size_t)(n0 + sr) * 256 + sc;
  const short* Br1 = W0 + (size_t)(n0 + 64 + sr) * 256 + sc;
  const int wo = wave << 9;

  const int ar = tid >> 2;            // A-stage: 4 threads per row, 8 cols
  const int ac = (tid & 3) << 3;
  const size_t abase = (size_t)(tok0 + ar) * 256 + ac;
  const float s_r = scale[ar];

  f32x4 acc[4][2] = {};

  for (int t = 0; t < 8; ++t) {
    const int kt = t << 5;
    // stage A chunk: load (L2-hot), rms-scale, round to bf16, ds_write
    {
      s16x8 o0;
      if (mode == 0) {
        s16x8 f0 = *(const s16x8*)&yf[abase + kt];
        s16x8 c0 = *(const s16x8*)&yb[abase + kt];
        #pragma unroll
        for (int e = 0; e < 8; ++e)
          o0[e] = f2bf((0.5f * (bf2f(f0[e]) + bf2f(c0[e])) * s_r) * rw[kt + ac + e]);
      } else {
        s16x8 f0 = *(const s16x8*)&ysel[abase + kt];
        #pragma unroll
        for (int e = 0; e < 8; ++e)
          o0[e] = f2bf((bf2f(f0[e]) * s_r) * rw[kt + ac + e]);
      }
      *(s16x8*)&As[(ar << 5) + ac] = o0;
    }
    gl_lds16(Br0 + kt, &Bs[wo]);
    gl_lds16(Br1 + kt, &Bs[wo + 2048]);
    __syncthreads();
    s16x8 af[4], bfr[2];
    #pragma unroll
    for (int i = 0; i < 4; ++i)
      af[i] = *(const s16x8*)&As[(((i << 4) + mf) << 5) + (kq << 3)];
    #pragma unroll
    for (int j = 0; j < 2; ++j)
      bfr[j] = *(const s16x8*)&Bs[((wn + (j << 4) + mf) << 5) + (kq << 3)];
    #pragma unroll
    for (int i = 0; i < 4; ++i)
      #pragma unroll
      for (int j = 0; j < 2; ++j)
        acc[i][j] = __builtin_amdgcn_mfma_f32_16x16x32_bf16(af[i], bfr[j], acc[i][j], 0, 0, 0);
    __syncthreads();
  }

  #pragma unroll
  for (int i = 0; i < 4; ++i) {
    int gm = m0 + (i << 4) + (kq << 2);
    int tok = gm & 8191;                 // 4-aligned; never crosses 4096
    int bb2 = tok >> 12, ll = tok & 4095;
    #pragma unroll
    for (int j = 0; j < 2; ++j) {
      int gn = n0 + wn + (j << 4) + mf;
      // skip = in0[b][gn][l..l+3] (contiguous f32x4)
      f32x4 sk = *(const f32x4*)&in0[((((size_t)(bb2 << 8)) + gn) << 12) + ll];
      #pragma unroll
      for (int r = 0; r < 4; ++r) {
        float v = acc[i][j][r] + sk[r];
        Cb[(size_t)(gm + r) * 256 + gn] = f2bf(v);
      }
    }
  }
}

// ---------------------------------------------------------------------------
extern "C" void kernel_launch(void* const* d_in, const int* in_sizes, int n_in,
                              void* d_out, int out_size, void* d_ws, size_t ws_size,
                              hipStream_t stream) {
  const float* in0        = (const float*)d_in[0];
  const float* in1        = (const float*)d_in[1];
  const float* n0w        = (const float*)d_in[2];
  const float* n0b        = (const float*)d_in[3];
  const float* n1w        = (const float*)d_in[4];
  const float* n1b        = (const float*)d_in[5];
  const float* in_proj_w  = (const float*)d_in[6];
  const float* in_projz_w = (const float*)d_in[7];
  const float* conv1d_w   = (const float*)d_in[8];
  const float* conv1d_b   = (const float*)d_in[9];
  const float* conv1db_w  = (const float*)d_in[10];
  const float* conv1db_b  = (const float*)d_in[11];
  const float* xproj_w    = (const float*)d_in[12];
  const float* xprojb_w   = (const float*)d_in[13];
  const float* dtproj_w   = (const float*)d_in[14];
  const float* dtproj_b   = (const float*)d_in[15];
  const float* dtprojb_w  = (const float*)d_in[16];
  const float* dtprojb_b  = (const float*)d_in[17];
  const float* A_log      = (const float*)d_in[18];
  const float* Ab_log     = (const float*)d_in[19];
  const float* D_p        = (const float*)d_in[20];
  const float* D_b        = (const float*)d_in[21];
  const float* rms_w      = (const float*)d_in[22];
  const float* out_proj_w = (const float*)d_in[23];
  const float* conv3d_w   = (const float*)d_in[24];
  const float* conv3d_b   = (const float*)d_in[25];
  (void)in_sizes; (void)n_in; (void)out_size; (void)ws_size;

  float* ws = (float*)d_ws;
  size_t o = 0;
  short* xlnz = (short*)(ws + o); o += 2097152;   // 16384x256 bf16
  float* x    = ws + o;           o += 2097152;   // x then z contiguous
  float* z    = ws + o;           o += 2097152;
  float* xc2  = ws + o;           o += 4194304;   // 2 dirs x 8192x256 f32
  float* dbl2 = ws + o;           o += 524288;    // 2 dirs x 8192x32
  float* P    = ws + o;           o += 2097152;   // 2 dirs x 1M
  float* Q    = ws + o;           o += 2097152;
  float* Hs   = ws + o;           o += 2097152;
  short* yall = (short*)(ws + o); o += 2097152;   // 2 dirs x 8192x256 bf16
  short* obuf = (short*)(ws + o); o += 3145728;
  short* Wx   = (short*)(ws + o); o += 32768;
  short* Wz   = (short*)(ws + o); o += 32768;
  short* Wo   = (short*)(ws + o); o += 32768;
  short* Wc   = (short*)(ws + o); o += 163840;    // 1280x256 bf16 padded
  float* out  = (float*)d_out;

  dim3 blk(256);

  ln_transpose_kernel<<<dim3(512), blk, 0, stream>>>(
      in0, in1, n0w, n0b, n1w, n1b,
      in_proj_w, in_projz_w, out_proj_w, conv3d_w, Wx, Wz, Wo, Wc,
      xlnz);

  // in_proj: x|z batched (M=16384, weight switch at 8192)
  gemm_fast<0><<<dim3(2, 128), blk, 0, stream>>>(xlnz, Wx, Wz, x, nullptr, nullptr, nullptr, 8192);

  // both directions: conv+silu -> xproj -> dtproj -> scan p1
  fused_front<<<dim3(1024), blk, 0, stream>>>(
      x, conv1d_w, conv1d_b, conv1db_w, conv1db_b,
      xproj_w, xprojb_w, dtproj_w, dtproj_b, dtprojb_w, dtprojb_b,
      A_log, Ab_log, xc2, dbl2, P, Q);

  scan_p2<<<dim3(128), dim3(64), 0, stream>>>(P, Q, Hs);

  scan_p3<<<dim3(1024), blk, 0, stream>>>(
      xc2, dbl2, dtproj_w, dtproj_b, dtprojb_w, dtprojb_b,
      Hs, z, A_log, Ab_log, D_p, D_b, yall);

  // heads: rms fused into out_proj+skip (batched) -> conv3d (batched)
  gemm_rms_epi1<<<dim3(2, 384), blk, 0, stream>>>(yall, Wo, rms_w, obuf, in0);
  gemm_fast<2><<<dim3(10, 192), blk, 0, stream>>>(obuf, Wc, nullptr, out, nullptr, nullptr, conv3d_b, 0);
}